// Round 2
// baseline (2596.180 us; speedup 1.0000x reference)
//
#include <hip/hip_runtime.h>
#include <cstdint>
#include <cstddef>

#define NN 131072
#define EE 524288
#define BB 4096
#define LL 768
#define RS 776  // LDS row stride (shorts) for conv buffers: 776*2=1552 B, 16B-aligned rows

// ---------- helpers ----------
__device__ __forceinline__ float b2f(unsigned short u) {
  return __uint_as_float(((unsigned int)u) << 16);
}
__device__ __forceinline__ unsigned short f2b(float f) {
  unsigned int x = __float_as_uint(f);
  x += 0x7fff + ((x >> 16) & 1);  // RNE
  return (unsigned short)(x >> 16);
}
__device__ __forceinline__ float sigm(float x) { return 1.f / (1.f + expf(-x)); }
__device__ __forceinline__ float softplus_(float x) {
  return fmaxf(x, 0.f) + log1pf(expf(-fabsf(x)));
}

// ---------- zero fill (no hipMemsetAsync: keep graph capture trivially safe) ----------
__global__ __launch_bounds__(256) void k_zerof(float* __restrict__ p) {
  p[(size_t)blockIdx.x * 256 + threadIdx.x] = 0.f;
}
__global__ __launch_bounds__(256) void k_zero4(float4* __restrict__ p) {
  p[(size_t)blockIdx.x * 256 + threadIdx.x] = make_float4(0.f, 0.f, 0.f, 0.f);
}

// ---------- GCN ----------
__global__ __launch_bounds__(256) void k_deg(const int* __restrict__ ei,
                                             float* __restrict__ cnt) {
  int e = blockIdx.x * 256 + threadIdx.x;
  atomicAdd(&cnt[ei[EE + e]], 1.0f);
}

__global__ __launch_bounds__(256) void k_dinv(float* __restrict__ d) {
  int i = blockIdx.x * 256 + threadIdx.x;
  d[i] = rsqrtf(d[i] + 1.0f);
}

// g[i][f] = dinv[i] * (drug[i,:9] @ W[9,64])[f]
__global__ __launch_bounds__(256) void k_mm1(const float* __restrict__ drug,
                                             const float* __restrict__ W,
                                             const float* __restrict__ dinv,
                                             float* __restrict__ g) {
  __shared__ float Ws[9 * 64];
  int t = threadIdx.x;
  for (int i = t; i < 576; i += 256) Ws[i] = W[i];
  __syncthreads();
  int node = blockIdx.x * 4 + (t >> 6);
  int f = t & 63;
  const float* dr = drug + (size_t)node * 9;
  float s = 0.f;
#pragma unroll
  for (int k = 0; k < 9; k++) s += dr[k] * Ws[k * 64 + f];
  g[(size_t)node * 64 + f] = dinv[node] * s;
}

// g[i][f] = dinv[i] * (x[i,:64] @ W[64,64])[f]
__global__ __launch_bounds__(256) void k_mm2(const float* __restrict__ x,
                                             const float* __restrict__ W,
                                             const float* __restrict__ dinv,
                                             float* __restrict__ g) {
  __shared__ float Ws[64 * 64];
  __shared__ float xs[4][64];
  int t = threadIdx.x;
  for (int i = t; i < 4096; i += 256) Ws[i] = W[i];
  int node = blockIdx.x * 4 + (t >> 6);
  int f = t & 63;
  xs[t >> 6][f] = x[(size_t)node * 64 + f];
  __syncthreads();
  const float* xr = xs[t >> 6];
  float s = 0.f;
#pragma unroll
  for (int k = 0; k < 64; k++) s += xr[k] * Ws[k * 64 + f];
  g[(size_t)node * 64 + f] = dinv[node] * s;
}

// acc[dst][f] += g[src][f]  (one 64-lane group per edge, lane = feature)
__global__ __launch_bounds__(256) void k_edge(const int* __restrict__ ei,
                                              const float* __restrict__ g,
                                              float* __restrict__ acc) {
  int t = threadIdx.x;
  int e = blockIdx.x * 4 + (t >> 6);
  int f = t & 63;
  int src = ei[e];
  int dst = ei[EE + e];
  atomicAdd(&acc[(size_t)dst * 64 + f], g[(size_t)src * 64 + f]);
}

template <bool TANH>
__global__ __launch_bounds__(256) void k_post(const float* __restrict__ acc,
                                              const float* __restrict__ g,
                                              const float* __restrict__ dinv,
                                              const float* __restrict__ b,
                                              float* __restrict__ xout) {
  size_t i = (size_t)blockIdx.x * 256 + threadIdx.x;
  int node = (int)(i >> 6);
  int f = (int)(i & 63);
  float v = dinv[node] * (acc[i] + g[i]) + b[f];
  xout[i] = TANH ? tanhf(v) : v;
}

// pooled[g][0:64]=max, [64:128]=mean over the 32 consecutive nodes of graph g
__global__ __launch_bounds__(256) void k_pool(const float* __restrict__ x,
                                              float* __restrict__ pooled) {
  int t = threadIdx.x;
  int gph = blockIdx.x * 4 + (t >> 6);
  int f = t & 63;
  const float* p = x + (size_t)gph * 32 * 64 + f;
  float mx = -1e30f, sm = 0.f;
#pragma unroll 8
  for (int j = 0; j < 32; j++) {
    float v = p[(size_t)j * 64];
    mx = fmaxf(mx, v);
    sm += v;
  }
  pooled[(size_t)gph * 128 + f] = mx;
  pooled[(size_t)gph * 128 + 64 + f] = sm * (1.f / 32.f);
}

// gout[g][o] = pooled[g,:128] @ out_W[128,768] + out_b  (8 graphs / block)
__global__ __launch_bounds__(256) void k_outmm(const float* __restrict__ pooled,
                                               const float* __restrict__ W,
                                               const float* __restrict__ bias,
                                               float* __restrict__ gout) {
  __shared__ float ps[8][128];
  int t = threadIdx.x;
  int g0 = blockIdx.x * 8;
  for (int i = t; i < 8 * 128; i += 256) ps[i >> 7][i & 127] = pooled[(size_t)g0 * 128 + i];
  __syncthreads();
  float a0[8], a1[8], a2[8];
#pragma unroll
  for (int j = 0; j < 8; j++) { a0[j] = 0.f; a1[j] = 0.f; a2[j] = 0.f; }
  for (int k = 0; k < 128; k++) {
    float w0 = W[k * 768 + t];
    float w1 = W[k * 768 + t + 256];
    float w2 = W[k * 768 + t + 512];
#pragma unroll
    for (int j = 0; j < 8; j++) {
      float p = ps[j][k];
      a0[j] += p * w0; a1[j] += p * w1; a2[j] += p * w2;
    }
  }
  float b0 = bias[t], b1 = bias[t + 256], b2 = bias[t + 512];
  for (int j = 0; j < 8; j++) {
    gout[(size_t)(g0 + j) * 768 + t]       = a0[j] + b0;
    gout[(size_t)(g0 + j) * 768 + t + 256] = a1[j] + b1;
    gout[(size_t)(g0 + j) * 768 + t + 512] = a2[j] + b2;
  }
}

// 32ch x 32ch k=3 conv over bf16 LDS buffers; positions stored at index l+1.
// Thread (og=t>>5, lq=t&31) computes 4 out-channels x 8 positions per chunk c.
template <bool STATS>
__device__ __forceinline__ void conv32x32(const unsigned short* in, const unsigned short* Wsh,
                                          const float* bsh, unsigned short* outbuf,
                                          int t, float* tmax, float* tsum) {
  const int og = t >> 5, lq = t & 31;
  for (int c = 0; c < 3; c++) {
    const int base = c * 256 + lq * 8;  // 16B-aligned within row
    float acc[4][8];
#pragma unroll
    for (int a = 0; a < 4; a++) {
      float bv = bsh[og * 4 + a];
#pragma unroll
      for (int j = 0; j < 8; j++) acc[a][j] = bv;
    }
    for (int i = 0; i < 32; i++) {
      float x[10];
      const unsigned short* row = &in[i * RS + base];
#pragma unroll
      for (int q = 0; q < 10; q++) x[q] = b2f(row[q]);
#pragma unroll
      for (int a = 0; a < 4; a++) {
        const unsigned short* w = &Wsh[(og * 4 + a) * 96 + i * 3];
        float w0 = b2f(w[0]), w1 = b2f(w[1]), w2 = b2f(w[2]);
#pragma unroll
        for (int j = 0; j < 8; j++)
          acc[a][j] += w0 * x[j] + w1 * x[j + 1] + w2 * x[j + 2];
      }
    }
#pragma unroll
    for (int a = 0; a < 4; a++) {
      int o = og * 4 + a;
#pragma unroll
      for (int j = 0; j < 8; j++) {
        float v = acc[a][j];
        if (STATS) { tmax[a] = fmaxf(tmax[a], v); tsum[a] += v; }
        outbuf[o * RS + base + 1 + j] = f2b(v);
      }
    }
  }
}

// ---------- fully fused CNN chain: conv1..3 + CBAM + spatial + maxpool2 -> pvec ----------
// One block per graph. All intermediates in LDS (~124 KB) -> no h2 global buffer.
__global__ __launch_bounds__(256) void k_cnn(
    const float* __restrict__ gout, const float* __restrict__ protein,
    const float* __restrict__ W1, const float* __restrict__ b1,
    const float* __restrict__ W2, const float* __restrict__ b2,
    const float* __restrict__ W3, const float* __restrict__ b3,
    const float* __restrict__ caW1, const float* __restrict__ caW2,
    const float* __restrict__ samW, const float* __restrict__ samb,
    unsigned short* __restrict__ pvec) {
  __shared__ float comb[2][772];                       // pos l at idx l+1, zero halo
  __shared__ alignas(16) unsigned short h1buf[32 * RS];  // h1, then reused for h3
  __shared__ alignas(16) unsigned short h2buf[32 * RS];  // h2, then reused as fp32 scratch
  __shared__ float W1s[192];
  __shared__ unsigned short W2s[3072], W3s[3072];
  __shared__ float b1s[32], b2s[32], b3s[32];
  __shared__ float caW1s[512], caW2s[512], samWs[8];
  __shared__ float cmax[32], csum[32], t1buf[2][16], feats[32];
  const int t = threadIdx.x;
  const int b = blockIdx.x;

  // stage weights
  for (int i = t; i < 192; i += 256) W1s[i] = W1[i];
  for (int i = t; i < 3072; i += 256) { W2s[i] = f2b(W2[i]); W3s[i] = f2b(W3[i]); }
  for (int i = t; i < 512; i += 256) { caW1s[i] = caW1[i]; caW2s[i] = caW2[i]; }
  if (t < 32) { b1s[t] = b1[t]; b2s[t] = b2[t]; b3s[t] = b3[t]; }
  if (t >= 64 && t < 70) samWs[t - 64] = samW[t - 64];
  if (t == 70) samWs[6] = samb[0];
  // zero halo slots (idx 0 and 769) of h1/h2 rows; conv writes touch only [1,768]
  if (t < 128) {
    int o = t >> 2, which = t & 3;
    unsigned short* buf = (which & 2) ? h2buf : h1buf;
    buf[o * RS + ((which & 1) ? 769 : 0)] = 0;
  }
  // load comb (pos l in [-1,770) at idx l+1), zero outside [0,768)
  for (int i = t; i < 2 * 772; i += 256) {
    int ch = i / 772, li = i - ch * 772;
    int l = li - 1;
    float v = 0.f;
    if (l >= 0 && l < LL) v = ch ? protein[(size_t)b * LL + l] : gout[(size_t)b * LL + l];
    comb[ch][li] = v;
  }
  __syncthreads();

  // conv1 -> h1 (bf16)
  for (int o = 0; o < 32; o++) {
    float w0 = W1s[o * 6 + 0], w1 = W1s[o * 6 + 1], w2 = W1s[o * 6 + 2];
    float w3 = W1s[o * 6 + 3], w4 = W1s[o * 6 + 4], w5 = W1s[o * 6 + 5];
    float bv = b1s[o];
    for (int l = t; l < LL; l += 256) {
      float s = bv + w0 * comb[0][l] + w1 * comb[0][l + 1] + w2 * comb[0][l + 2]
                   + w3 * comb[1][l] + w4 * comb[1][l + 1] + w5 * comb[1][l + 2];
      h1buf[o * RS + l + 1] = f2b(s);
    }
  }
  __syncthreads();

  // conv2: h1 -> h2
  float dummy[4];
  conv32x32<false>(h1buf, W2s, b2s, h2buf, t, dummy, dummy);
  __syncthreads();

  // conv3: h2 -> h3 (into h1buf), track per-thread channel stats
  float tmax[4], tsum[4];
#pragma unroll
  for (int a = 0; a < 4; a++) { tmax[a] = -1e30f; tsum[a] = 0.f; }
  conv32x32<true>(h2buf, W3s, b3s, h1buf, t, tmax, tsum);

  // per-channel stats: reduce across the 32 lq threads of each og group
  const int og = t >> 5, lq = t & 31;
#pragma unroll
  for (int a = 0; a < 4; a++) {
    float m = tmax[a], s = tsum[a];
    for (int d = 16; d > 0; d >>= 1) {
      m = fmaxf(m, __shfl_xor(m, d, 32));
      s += __shfl_xor(s, d, 32);
    }
    if (lq == 0) { cmax[og * 4 + a] = m; csum[og * 4 + a] = s; }
  }
  __syncthreads();

  // channel-attention MLP: relu((v@W1^T)@W2^T) for max & mean, sum, sigmoid
  if (t < 32) {
    int j = t & 15;
    int mean = t >> 4;
    float s = 0.f;
    for (int o = 0; o < 32; o++) {
      float v = mean ? csum[o] * (1.f / 768.f) : cmax[o];
      s += v * caW1s[j * 32 + o];
    }
    t1buf[mean][j] = s;
  }
  __syncthreads();
  if (t < 32) {
    float m1 = 0.f, m2 = 0.f;
    for (int j = 0; j < 16; j++) {
      m1 += t1buf[0][j] * caW2s[t * 16 + j];
      m2 += t1buf[1][j] * caW2s[t * 16 + j];
    }
    feats[t] = sigm(fmaxf(m1, 0.f) + fmaxf(m2, 0.f));
  }
  __syncthreads();

  // spatial attention: reuse h2buf as fp32 scratch (h2 dead)
  float* xm = reinterpret_cast<float*>(h2buf);
  float* xM = xm + 772;
  float* att = xm + 1544;
  for (int l = t; l < LL; l += 256) {
    float sm = 0.f, mx = -1e30f;
    for (int ch = 0; ch < 32; ch++) {
      float v = b2f(h1buf[ch * RS + l + 1]) * feats[ch];
      sm += v;
      mx = fmaxf(mx, v);
    }
    xm[l] = sm * (1.f / 32.f);
    xM[l] = mx;
  }
  __syncthreads();
  for (int l = t; l < LL; l += 256) {
    float a = samWs[6];
#pragma unroll
    for (int k = 0; k < 3; k++) {
      int ll = l + k - 1;
      float vm = (ll >= 0 && ll < LL) ? xm[ll] : 0.f;
      float vM = (ll >= 0 && ll < LL) ? xM[ll] : 0.f;
      a += samWs[k] * vm + samWs[3 + k] * vM;
    }
    att[l] = sigm(a);
  }
  __syncthreads();

  // scale + maxpool2 + flatten (ch*384+lp) -> pvec bf16
  for (int idx = t; idx < 32 * 384; idx += 256) {
    int ch = idx / 384;
    int lp = idx - ch * 384;
    int l = lp * 2;
    float f = feats[ch];
    float v0 = b2f(h1buf[ch * RS + l + 1]) * f * att[l];
    float v1 = b2f(h1buf[ch * RS + l + 2]) * f * att[l + 1];
    pvec[(size_t)b * 12288 + idx] = f2b(fmaxf(v0, v1));
  }
}

// W1t[k*32+o] = lin1_W[o*12288+k]
__global__ __launch_bounds__(256) void k_transw(const float* __restrict__ W,
                                                float* __restrict__ Wt) {
  int idx = blockIdx.x * 256 + threadIdx.x;
  int k = idx >> 5, o = idx & 31;
  Wt[idx] = W[(size_t)o * 12288 + k];
}

// MLP head: 16 graphs/block; W1t streamed once per block as dense float4 rows
__global__ __launch_bounds__(256) void k_mlp(
    const unsigned short* __restrict__ pvec, const float* __restrict__ W1t,
    const float* __restrict__ lb1, const float* __restrict__ W2,
    const float* __restrict__ lb2, const float* __restrict__ W3,
    const float* __restrict__ lb3, float* __restrict__ out) {
  __shared__ float sred[16][16][32];  // [ks][g][o]
  __shared__ float s1[16][32];
  __shared__ float s2[16][32];
  const int t = threadIdx.x;
  const int g = t & 15;
  const int ks = t >> 4;
  const size_t gg = (size_t)blockIdx.x * 16 + g;
  const unsigned short* pv = pvec + gg * 12288;
  float acc[32];
#pragma unroll
  for (int o = 0; o < 32; o++) acc[o] = 0.f;
  for (int j = 0; j < 768; j++) {
    int k = ks + 16 * j;
    float v = b2f(pv[k]);
    const float4* w4 = reinterpret_cast<const float4*>(W1t + (size_t)k * 32);
#pragma unroll
    for (int q = 0; q < 8; q++) {
      float4 w = w4[q];
      acc[q * 4 + 0] += v * w.x;
      acc[q * 4 + 1] += v * w.y;
      acc[q * 4 + 2] += v * w.z;
      acc[q * 4 + 3] += v * w.w;
    }
  }
#pragma unroll
  for (int o = 0; o < 32; o++) sred[ks][g][o] = acc[o];
  __syncthreads();
#pragma unroll
  for (int p = 0; p < 2; p++) {
    int idx = t * 2 + p;
    int gi = idx >> 5, o = idx & 31;
    float s = 0.f;
#pragma unroll
    for (int kk = 0; kk < 16; kk++) s += sred[kk][gi][o];
    s1[gi][o] = softplus_(s + lb1[o]);
  }
  __syncthreads();
#pragma unroll
  for (int p = 0; p < 2; p++) {
    int idx = t * 2 + p;
    int gi = idx >> 5, o = idx & 31;
    float s = lb2[o];
    for (int kk = 0; kk < 32; kk++) s += s1[gi][kk] * W2[o * 32 + kk];
    s2[gi][o] = softplus_(s);
  }
  __syncthreads();
  if (t < 16) {
    float s = lb3[0];
    for (int kk = 0; kk < 32; kk++) s += s2[t][kk] * W3[kk];
    out[blockIdx.x * 16 + t] = softplus_(s);
  }
}

extern "C" void kernel_launch(void* const* d_in, const int* in_sizes, int n_in,
                              void* d_out, int out_size, void* d_ws, size_t ws_size,
                              hipStream_t stream) {
  const float* drug    = (const float*)d_in[0];
  const int*   ei      = (const int*)d_in[1];
  // d_in[2] batch_index: arange(N)//32 (sorted, exactly 32 nodes/graph) — used implicitly
  const float* protein = (const float*)d_in[3];
  const float* g1W = (const float*)d_in[4];
  const float* g1b = (const float*)d_in[5];
  const float* g2W = (const float*)d_in[6];
  const float* g2b = (const float*)d_in[7];
  const float* oW  = (const float*)d_in[8];
  const float* ob  = (const float*)d_in[9];
  const float* c1W = (const float*)d_in[10];
  const float* c1b = (const float*)d_in[11];
  const float* c2W = (const float*)d_in[12];
  const float* c2b = (const float*)d_in[13];
  const float* c3W = (const float*)d_in[14];
  const float* c3b = (const float*)d_in[15];
  const float* caW1 = (const float*)d_in[16];
  const float* caW2 = (const float*)d_in[17];
  const float* samW = (const float*)d_in[18];
  const float* samb = (const float*)d_in[19];
  const float* l1W = (const float*)d_in[20];
  const float* l1b = (const float*)d_in[21];
  const float* l2W = (const float*)d_in[22];
  const float* l2b = (const float*)d_in[23];
  const float* l3W = (const float*)d_in[24];
  const float* l3b = (const float*)d_in[25];

  // Workspace map (peak usage EXACTLY 112 MiB = 117,440,512 B; round-0's 304 MiB
  // overflowed ws and faulted):
  char* ws = (char*)d_ws;
  float* dinv   = (float*)(ws);                      // [0, 0.5M)
  float* acc    = (float*)(ws + (size_t)524288);     // [0.5M, 32.5M)
  float* g      = (float*)(ws + (size_t)34078720);   // [32.5M, 64.5M)
  float* x      = (float*)(ws + (size_t)67633152);   // [64.5M, 96.5M)
  float* pooled = (float*)(ws + (size_t)101187584);  // [96.5M, 98.5M)
  float* gout   = (float*)(ws + (size_t)103284736);  // [98.5M, 110.5M)
  float* W1t    = (float*)(ws + (size_t)115867648);  // [110.5M, 112M)
  // pvec overlays acc/g/x (all dead once the CNN stage runs); ends at pooled's start
  unsigned short* pvec = (unsigned short*)(ws + (size_t)524288);
  float* outp = (float*)d_out;

  // degree -> dinv
  k_zerof<<<NN / 256, 256, 0, stream>>>(dinv);
  k_deg<<<EE / 256, 256, 0, stream>>>(ei, dinv);
  k_dinv<<<NN / 256, 256, 0, stream>>>(dinv);
  // W1 transpose (independent of everything above)
  k_transw<<<(12288 * 32) / 256, 256, 0, stream>>>(l1W, W1t);

  // GCN layer 1
  k_mm1<<<NN / 4, 256, 0, stream>>>(drug, g1W, dinv, g);
  k_zero4<<<NN * 64 / 4 / 256, 256, 0, stream>>>((float4*)acc);
  k_edge<<<EE / 4, 256, 0, stream>>>(ei, g, acc);
  k_post<true><<<NN * 64 / 256, 256, 0, stream>>>(acc, g, dinv, g1b, x);
  // GCN layer 2
  k_mm2<<<NN / 4, 256, 0, stream>>>(x, g2W, dinv, g);
  k_zero4<<<NN * 64 / 4 / 256, 256, 0, stream>>>((float4*)acc);
  k_edge<<<EE / 4, 256, 0, stream>>>(ei, g, acc);
  k_post<true><<<NN * 64 / 256, 256, 0, stream>>>(acc, g, dinv, g2b, x);
  // GCN layer 3 (same weights, no activation)
  k_mm2<<<NN / 4, 256, 0, stream>>>(x, g2W, dinv, g);
  k_zero4<<<NN * 64 / 4 / 256, 256, 0, stream>>>((float4*)acc);
  k_edge<<<EE / 4, 256, 0, stream>>>(ei, g, acc);
  k_post<false><<<NN * 64 / 256, 256, 0, stream>>>(acc, g, dinv, g2b, x);

  // pool + output linear
  k_pool<<<BB / 4, 256, 0, stream>>>(x, pooled);
  k_outmm<<<BB / 8, 256, 0, stream>>>(pooled, oW, ob, gout);

  // fused CNN chain + CBAM + maxpool (writes pvec over the dead GCN buffers)
  k_cnn<<<BB, 256, 0, stream>>>(gout, protein, c1W, c1b, c2W, c2b, c3W, c3b,
                                caW1, caW2, samW, samb, pvec);

  // MLP head
  k_mlp<<<BB / 16, 256, 0, stream>>>(pvec, W1t, l1b, l2W, l2b, l3W, l3b, outp);
}

// Round 3
// 1361.006 us; speedup vs baseline: 1.9075x; 1.9075x over previous
//
#include <hip/hip_runtime.h>
#include <cstdint>
#include <cstddef>

#define NN 131072
#define EE 524288
#define BB 4096
#define LL 768

typedef __attribute__((ext_vector_type(8))) short bf16x8;
typedef __attribute__((ext_vector_type(4))) float f32x4;
typedef __attribute__((ext_vector_type(2))) unsigned int uint2v;
typedef __attribute__((ext_vector_type(4))) unsigned int uint4v;

// ---------- helpers ----------
__device__ __forceinline__ float b2f(unsigned short u) {
  return __uint_as_float(((unsigned int)u) << 16);
}
__device__ __forceinline__ unsigned short f2b(float f) {
  unsigned int x = __float_as_uint(f);
  x += 0x7fff + ((x >> 16) & 1);  // RNE
  return (unsigned short)(x >> 16);
}
__device__ __forceinline__ float sigm(float x) { return 1.f / (1.f + expf(-x)); }
__device__ __forceinline__ float softplus_(float x) {
  return fmaxf(x, 0.f) + log1pf(expf(-fabsf(x)));
}

// ---------- zero fill ----------
__global__ __launch_bounds__(256) void k_zerof(float* __restrict__ p) {
  p[(size_t)blockIdx.x * 256 + threadIdx.x] = 0.f;
}
__global__ __launch_bounds__(256) void k_zero4(float4* __restrict__ p) {
  p[(size_t)blockIdx.x * 256 + threadIdx.x] = make_float4(0.f, 0.f, 0.f, 0.f);
}

// ---------- GCN ----------
__global__ __launch_bounds__(256) void k_deg(const int* __restrict__ ei,
                                             float* __restrict__ cnt) {
  int e = blockIdx.x * 256 + threadIdx.x;
  atomicAdd(&cnt[ei[EE + e]], 1.0f);
}

__global__ __launch_bounds__(256) void k_dinv(float* __restrict__ d) {
  int i = blockIdx.x * 256 + threadIdx.x;
  d[i] = rsqrtf(d[i] + 1.0f);
}

__global__ __launch_bounds__(256) void k_mm1(const float* __restrict__ drug,
                                             const float* __restrict__ W,
                                             const float* __restrict__ dinv,
                                             float* __restrict__ g) {
  __shared__ float Ws[9 * 64];
  int t = threadIdx.x;
  for (int i = t; i < 576; i += 256) Ws[i] = W[i];
  __syncthreads();
  int node = blockIdx.x * 4 + (t >> 6);
  int f = t & 63;
  const float* dr = drug + (size_t)node * 9;
  float s = 0.f;
#pragma unroll
  for (int k = 0; k < 9; k++) s += dr[k] * Ws[k * 64 + f];
  g[(size_t)node * 64 + f] = dinv[node] * s;
}

__global__ __launch_bounds__(256) void k_mm2(const float* __restrict__ x,
                                             const float* __restrict__ W,
                                             const float* __restrict__ dinv,
                                             float* __restrict__ g) {
  __shared__ float Ws[64 * 64];
  __shared__ float xs[4][64];
  int t = threadIdx.x;
  for (int i = t; i < 4096; i += 256) Ws[i] = W[i];
  int node = blockIdx.x * 4 + (t >> 6);
  int f = t & 63;
  xs[t >> 6][f] = x[(size_t)node * 64 + f];
  __syncthreads();
  const float* xr = xs[t >> 6];
  float s = 0.f;
#pragma unroll
  for (int k = 0; k < 64; k++) s += xr[k] * Ws[k * 64 + f];
  g[(size_t)node * 64 + f] = dinv[node] * s;
}

__global__ __launch_bounds__(256) void k_edge(const int* __restrict__ ei,
                                              const float* __restrict__ g,
                                              float* __restrict__ acc) {
  int t = threadIdx.x;
  int e = blockIdx.x * 4 + (t >> 6);
  int f = t & 63;
  int src = ei[e];
  int dst = ei[EE + e];
  atomicAdd(&acc[(size_t)dst * 64 + f], g[(size_t)src * 64 + f]);
}

template <bool TANH>
__global__ __launch_bounds__(256) void k_post(const float* __restrict__ acc,
                                              const float* __restrict__ g,
                                              const float* __restrict__ dinv,
                                              const float* __restrict__ b,
                                              float* __restrict__ xout) {
  size_t i = (size_t)blockIdx.x * 256 + threadIdx.x;
  int node = (int)(i >> 6);
  int f = (int)(i & 63);
  float v = dinv[node] * (acc[i] + g[i]) + b[f];
  xout[i] = TANH ? tanhf(v) : v;
}

__global__ __launch_bounds__(256) void k_pool(const float* __restrict__ x,
                                              float* __restrict__ pooled) {
  int t = threadIdx.x;
  int gph = blockIdx.x * 4 + (t >> 6);
  int f = t & 63;
  const float* p = x + (size_t)gph * 32 * 64 + f;
  float mx = -1e30f, sm = 0.f;
#pragma unroll 8
  for (int j = 0; j < 32; j++) {
    float v = p[(size_t)j * 64];
    mx = fmaxf(mx, v);
    sm += v;
  }
  pooled[(size_t)gph * 128 + f] = mx;
  pooled[(size_t)gph * 128 + 64 + f] = sm * (1.f / 32.f);
}

__global__ __launch_bounds__(256) void k_outmm(const float* __restrict__ pooled,
                                               const float* __restrict__ W,
                                               const float* __restrict__ bias,
                                               float* __restrict__ gout) {
  __shared__ float ps[8][128];
  int t = threadIdx.x;
  int g0 = blockIdx.x * 8;
  for (int i = t; i < 8 * 128; i += 256) ps[i >> 7][i & 127] = pooled[(size_t)g0 * 128 + i];
  __syncthreads();
  float a0[8], a1[8], a2[8];
#pragma unroll
  for (int j = 0; j < 8; j++) { a0[j] = 0.f; a1[j] = 0.f; a2[j] = 0.f; }
  for (int k = 0; k < 128; k++) {
    float w0 = W[k * 768 + t];
    float w1 = W[k * 768 + t + 256];
    float w2 = W[k * 768 + t + 512];
#pragma unroll
    for (int j = 0; j < 8; j++) {
      float p = ps[j][k];
      a0[j] += p * w0; a1[j] += p * w1; a2[j] += p * w2;
    }
  }
  float b0 = bias[t], b1 = bias[t + 256], b2 = bias[t + 512];
  for (int j = 0; j < 8; j++) {
    gout[(size_t)(g0 + j) * 768 + t]       = a0[j] + b0;
    gout[(size_t)(g0 + j) * 768 + t + 256] = a1[j] + b1;
    gout[(size_t)(g0 + j) * 768 + t + 512] = a2[j] + b2;
  }
}

// MFMA conv 32ch->32ch k=3 over position-major bf16 LDS (rows l+1, 32 shorts each).
// K reordered tau-major: k = tau*32 + i. A[m=lane&15][k=quad*8+j] from Wt[tau][o][i];
// B[k=quad*8+j][n=lane&15] = in row (l0+lx+tau); D row(M)=o=quad*4+r, col(N)=l=l0+lx.
template <bool STATS>
__device__ __forceinline__ void conv_mfma(const unsigned short* in, unsigned short* out,
                                          const unsigned short* Wt, const float* bias,
                                          int t, float tmax[2][4], float tsum[2][4]) {
  const int lane = t & 63, wv = t >> 6;
  const int lx = lane & 15, quad = lane >> 4;
  bf16x8 A[2][3];
  f32x4 cinit[2];
#pragma unroll
  for (int mt = 0; mt < 2; mt++) {
#pragma unroll
    for (int tau = 0; tau < 3; tau++)
      A[mt][tau] = *(const bf16x8*)&Wt[tau * 1024 + (mt * 16 + lx) * 32 + quad * 8];
#pragma unroll
    for (int r = 0; r < 4; r++) cinit[mt][r] = bias[mt * 16 + quad * 4 + r];
  }
  for (int n = 0; n < 12; n++) {
    const int l0 = (wv * 12 + n) * 16;
    bf16x8 Bf[3];
#pragma unroll
    for (int tau = 0; tau < 3; tau++)
      Bf[tau] = *(const bf16x8*)&in[(l0 + lx + tau) * 32 + quad * 8];
#pragma unroll
    for (int mt = 0; mt < 2; mt++) {
      f32x4 acc = cinit[mt];
#pragma unroll
      for (int tau = 0; tau < 3; tau++)
        acc = __builtin_amdgcn_mfma_f32_16x16x32_bf16(A[mt][tau], Bf[tau], acc, 0, 0, 0);
      uint2v pk;
      pk.x = f2b(acc[0]) | ((unsigned)f2b(acc[1]) << 16);
      pk.y = f2b(acc[2]) | ((unsigned)f2b(acc[3]) << 16);
      *(uint2v*)&out[(l0 + lx + 1) * 32 + mt * 16 + quad * 4] = pk;
      if (STATS) {
#pragma unroll
        for (int r = 0; r < 4; r++) {
          tmax[mt][r] = fmaxf(tmax[mt][r], acc[r]);
          tsum[mt][r] += acc[r];
        }
      }
    }
  }
}

// ---------- fully fused CNN chain (MFMA conv2/conv3) ----------
__global__ __launch_bounds__(256) void k_cnn(
    const float* __restrict__ gout, const float* __restrict__ protein,
    const float* __restrict__ W1, const float* __restrict__ b1,
    const float* __restrict__ W2, const float* __restrict__ b2,
    const float* __restrict__ W3, const float* __restrict__ b3,
    const float* __restrict__ caW1, const float* __restrict__ caW2,
    const float* __restrict__ samW, const float* __restrict__ samb,
    unsigned short* __restrict__ pvec) {
  __shared__ alignas(16) unsigned short h1t[770 * 32];  // h1, then h3 (rows l+1)
  __shared__ alignas(16) unsigned short h2t[770 * 32];  // comb(f32) -> h2 -> xm/xM/att(f32)
  __shared__ unsigned short W2t[3072], W3t[3072];       // [tau][o][i] bf16
  __shared__ float W1s[192];
  __shared__ float caW1s[512], caW2s[512];
  __shared__ float b1s[32], b2s[32], b3s[32], samWs[8];
  __shared__ float wmaxs[4][32], wsums[4][32];
  __shared__ float cmaxs[32], csums[32], t1buf[2][16], feats[32];
  float* h2f = (float*)h2t;
  const int t = threadIdx.x;
  const int b = blockIdx.x;
  const int lane = t & 63, wv = t >> 6, lx = lane & 15, quad = lane >> 4;

  // ---- S0: stage weights + comb; zero h1t halo rows ----
  for (int i = t; i < 192; i += 256) W1s[i] = W1[i];
  for (int i = t; i < 3072; i += 256) {
    int tau = i >> 10, rem = i & 1023, o = rem >> 5, ic = rem & 31;
    W2t[i] = f2b(W2[o * 96 + ic * 3 + tau]);
    W3t[i] = f2b(W3[o * 96 + ic * 3 + tau]);
  }
  for (int i = t; i < 512; i += 256) { caW1s[i] = caW1[i]; caW2s[i] = caW2[i]; }
  if (t < 32) { b1s[t] = b1[t]; b2s[t] = b2[t]; b3s[t] = b3[t]; }
  if (t >= 64 && t < 70) samWs[t - 64] = samW[t - 64];
  if (t == 70) samWs[6] = samb[0];
  if (t >= 128 && t < 192) {
    int z = t - 128;
    h1t[(z >= 32 ? 769 * 32 : 0) + (z & 31)] = 0;
  }
  for (int i = t; i < 1544; i += 256) {
    int ch = (i >= 772) ? 1 : 0;
    int li = i - ch * 772;
    int l = li - 1;
    float v = 0.f;
    if (l >= 0 && l < LL) v = ch ? protein[(size_t)b * LL + l] : gout[(size_t)b * LL + l];
    h2f[ch * 772 + li] = v;
  }
  __syncthreads();

  // ---- S1: conv1 (VALU), write position-major h1t ----
  {
    const int oct = t & 3;
    float wr[48], br[8];
#pragma unroll
    for (int a = 0; a < 8; a++) {
      int o = oct * 8 + a;
      br[a] = b1s[o];
#pragma unroll
      for (int q = 0; q < 6; q++) wr[a * 6 + q] = W1s[o * 6 + q];
    }
    const int lbase = t >> 2;
    for (int p = 0; p < 12; p++) {
      int l = lbase + p * 64;
      float c0 = h2f[l], c1 = h2f[l + 1], c2 = h2f[l + 2];
      float d0 = h2f[772 + l], d1 = h2f[772 + l + 1], d2 = h2f[772 + l + 2];
      uint4v pk;
#pragma unroll
      for (int a = 0; a < 4; a++) {
        const float* w0 = &wr[(2 * a) * 6];
        const float* w1 = &wr[(2 * a + 1) * 6];
        float s0 = br[2 * a]     + w0[0] * c0 + w0[1] * c1 + w0[2] * c2
                                 + w0[3] * d0 + w0[4] * d1 + w0[5] * d2;
        float s1 = br[2 * a + 1] + w1[0] * c0 + w1[1] * c1 + w1[2] * c2
                                 + w1[3] * d0 + w1[4] * d1 + w1[5] * d2;
        pk[a] = f2b(s0) | ((unsigned)f2b(s1) << 16);
      }
      *(uint4v*)&h1t[(l + 1) * 32 + oct * 8] = pk;
    }
  }
  __syncthreads();

  // ---- S2: zero h2t halo rows (comb dead) + MFMA conv2: h1t -> h2t ----
  if (t < 64) h2t[(t >= 32 ? 769 * 32 : 0) + (t & 31)] = 0;
  {
    float dm[2][4], ds[2][4];
    conv_mfma<false>(h1t, h2t, W2t, b2s, t, dm, ds);
  }
  __syncthreads();

  // ---- S3: MFMA conv3: h2t -> h1t (=h3), stats in registers ----
  float tmax[2][4], tsum[2][4];
#pragma unroll
  for (int mt = 0; mt < 2; mt++)
#pragma unroll
    for (int r = 0; r < 4; r++) { tmax[mt][r] = -1e30f; tsum[mt][r] = 0.f; }
  conv_mfma<true>(h2t, h1t, W3t, b3s, t, tmax, tsum);
#pragma unroll
  for (int mt = 0; mt < 2; mt++)
#pragma unroll
    for (int r = 0; r < 4; r++) {
      float m = tmax[mt][r], s = tsum[mt][r];
      for (int d = 1; d < 16; d <<= 1) {
        m = fmaxf(m, __shfl_xor(m, d));
        s += __shfl_xor(s, d);
      }
      if (lx == 0) {
        wmaxs[wv][mt * 16 + quad * 4 + r] = m;
        wsums[wv][mt * 16 + quad * 4 + r] = s;
      }
    }
  __syncthreads();

  // ---- S4: cross-wave stats + channel-attention MLP ----
  if (t < 32) {
    float m = wmaxs[0][t], s = wsums[0][t];
#pragma unroll
    for (int w = 1; w < 4; w++) { m = fmaxf(m, wmaxs[w][t]); s += wsums[w][t]; }
    cmaxs[t] = m;
    csums[t] = s;
  }
  __syncthreads();
  if (t < 32) {
    int j = t & 15;
    int mean = t >> 4;
    float s = 0.f;
    for (int o = 0; o < 32; o++) {
      float v = mean ? csums[o] * (1.f / 768.f) : cmaxs[o];
      s += v * caW1s[j * 32 + o];
    }
    t1buf[mean][j] = s;
  }
  __syncthreads();
  if (t < 32) {
    float m1 = 0.f, m2 = 0.f;
    for (int j = 0; j < 16; j++) {
      m1 += t1buf[0][j] * caW2s[t * 16 + j];
      m2 += t1buf[1][j] * caW2s[t * 16 + j];
    }
    feats[t] = sigm(fmaxf(m1, 0.f) + fmaxf(m2, 0.f));
  }
  __syncthreads();

  // ---- S5: spatial stats xm/xM per position (h2t dead -> f32 scratch) ----
  {
    const int oct = t & 3;
    float fr[8];
#pragma unroll
    for (int j = 0; j < 8; j++) fr[j] = feats[oct * 8 + j];
    const int lbase = t >> 2;
    for (int p = 0; p < 3; p++) {
      int l = lbase + p * 64 * 4;  // 12 iters worth folded: recompute below
      (void)l;
      break;
    }
    for (int p = 0; p < 12; p++) {
      int idx = t + p * 256;
      int l = idx >> 2;
      bf16x8 rv = *(const bf16x8*)&h1t[(l + 1) * 32 + oct * 8];
      float sm = 0.f, mx = -1e30f;
#pragma unroll
      for (int j = 0; j < 8; j++) {
        float v = b2f((unsigned short)rv[j]) * fr[j];
        sm += v;
        mx = fmaxf(mx, v);
      }
      sm += __shfl_xor(sm, 1);
      mx = fmaxf(mx, __shfl_xor(mx, 1));
      sm += __shfl_xor(sm, 2);
      mx = fmaxf(mx, __shfl_xor(mx, 2));
      if (oct == 0) {
        h2f[l] = sm * (1.f / 32.f);
        h2f[772 + l] = mx;
      }
    }
  }
  __syncthreads();

  // ---- S6: spatial attention conv + sigmoid ----
  for (int l = t; l < LL; l += 256) {
    float a = samWs[6];
#pragma unroll
    for (int k = 0; k < 3; k++) {
      int ll = l + k - 1;
      float vm = (ll >= 0 && ll < LL) ? h2f[ll] : 0.f;
      float vM = (ll >= 0 && ll < LL) ? h2f[772 + ll] : 0.f;
      a += samWs[k] * vm + samWs[3 + k] * vM;
    }
    h2f[1544 + l] = sigm(a);
  }
  __syncthreads();

  // ---- S7: scale + maxpool2, position-major pvec (coalesced u32 stores) ----
  unsigned* pout = (unsigned*)(pvec + (size_t)b * 12288);
  for (int p = 0; p < 24; p++) {
    int idx = t + p * 256;  // 0..6143
    int ch = (idx & 15) * 2;
    int lp = idx >> 4;
    unsigned a1 = *(const unsigned*)&h1t[(2 * lp + 1) * 32 + ch];
    unsigned a2 = *(const unsigned*)&h1t[(2 * lp + 2) * 32 + ch];
    float f0 = feats[ch], f1 = feats[ch + 1];
    float at0 = h2f[1544 + 2 * lp], at1 = h2f[1544 + 2 * lp + 1];
    float v0 = fmaxf(b2f((unsigned short)(a1 & 0xffff)) * f0 * at0,
                     b2f((unsigned short)(a2 & 0xffff)) * f0 * at1);
    float v1 = fmaxf(b2f((unsigned short)(a1 >> 16)) * f1 * at0,
                     b2f((unsigned short)(a2 >> 16)) * f1 * at1);
    pout[idx] = f2b(v0) | ((unsigned)f2b(v1) << 16);
  }
}

// W1t row p_idx matches pvec layout p_idx = lp*32 + ch  (orig k = ch*384 + lp)
__global__ __launch_bounds__(256) void k_transw(const float* __restrict__ W,
                                                float* __restrict__ Wt) {
  int idx = blockIdx.x * 256 + threadIdx.x;
  int p_idx = idx >> 5, o = idx & 31;
  int ch = p_idx & 31, lp = p_idx >> 5;
  Wt[idx] = W[(size_t)o * 12288 + ch * 384 + lp];
}

// MLP head: 16 graphs/block; W1t streamed once per block as dense float4 rows
__global__ __launch_bounds__(256) void k_mlp(
    const unsigned short* __restrict__ pvec, const float* __restrict__ W1t,
    const float* __restrict__ lb1, const float* __restrict__ W2,
    const float* __restrict__ lb2, const float* __restrict__ W3,
    const float* __restrict__ lb3, float* __restrict__ out) {
  __shared__ float sred[16][16][32];
  __shared__ float s1[16][32];
  __shared__ float s2[16][32];
  const int t = threadIdx.x;
  const int g = t & 15;
  const int ks = t >> 4;
  const size_t gg = (size_t)blockIdx.x * 16 + g;
  const unsigned short* pv = pvec + gg * 12288;
  float acc[32];
#pragma unroll
  for (int o = 0; o < 32; o++) acc[o] = 0.f;
  for (int j = 0; j < 768; j++) {
    int k = ks + 16 * j;
    float v = b2f(pv[k]);
    const float4* w4 = reinterpret_cast<const float4*>(W1t + (size_t)k * 32);
#pragma unroll
    for (int q = 0; q < 8; q++) {
      float4 w = w4[q];
      acc[q * 4 + 0] += v * w.x;
      acc[q * 4 + 1] += v * w.y;
      acc[q * 4 + 2] += v * w.z;
      acc[q * 4 + 3] += v * w.w;
    }
  }
#pragma unroll
  for (int o = 0; o < 32; o++) sred[ks][g][o] = acc[o];
  __syncthreads();
#pragma unroll
  for (int p = 0; p < 2; p++) {
    int idx = t * 2 + p;
    int gi = idx >> 5, o = idx & 31;
    float s = 0.f;
#pragma unroll
    for (int kk = 0; kk < 16; kk++) s += sred[kk][gi][o];
    s1[gi][o] = softplus_(s + lb1[o]);
  }
  __syncthreads();
#pragma unroll
  for (int p = 0; p < 2; p++) {
    int idx = t * 2 + p;
    int gi = idx >> 5, o = idx & 31;
    float s = lb2[o];
    for (int kk = 0; kk < 32; kk++) s += s1[gi][kk] * W2[o * 32 + kk];
    s2[gi][o] = softplus_(s);
  }
  __syncthreads();
  if (t < 16) {
    float s = lb3[0];
    for (int kk = 0; kk < 32; kk++) s += s2[t][kk] * W3[kk];
    out[blockIdx.x * 16 + t] = softplus_(s);
  }
}

extern "C" void kernel_launch(void* const* d_in, const int* in_sizes, int n_in,
                              void* d_out, int out_size, void* d_ws, size_t ws_size,
                              hipStream_t stream) {
  const float* drug    = (const float*)d_in[0];
  const int*   ei      = (const int*)d_in[1];
  const float* protein = (const float*)d_in[3];
  const float* g1W = (const float*)d_in[4];
  const float* g1b = (const float*)d_in[5];
  const float* g2W = (const float*)d_in[6];
  const float* g2b = (const float*)d_in[7];
  const float* oW  = (const float*)d_in[8];
  const float* ob  = (const float*)d_in[9];
  const float* c1W = (const float*)d_in[10];
  const float* c1b = (const float*)d_in[11];
  const float* c2W = (const float*)d_in[12];
  const float* c2b = (const float*)d_in[13];
  const float* c3W = (const float*)d_in[14];
  const float* c3b = (const float*)d_in[15];
  const float* caW1 = (const float*)d_in[16];
  const float* caW2 = (const float*)d_in[17];
  const float* samW = (const float*)d_in[18];
  const float* samb = (const float*)d_in[19];
  const float* l1W = (const float*)d_in[20];
  const float* l1b = (const float*)d_in[21];
  const float* l2W = (const float*)d_in[22];
  const float* l2b = (const float*)d_in[23];
  const float* l3W = (const float*)d_in[24];
  const float* l3b = (const float*)d_in[25];

  // Workspace map, peak 112 MiB (known-safe from round 2)
  char* ws = (char*)d_ws;
  float* dinv   = (float*)(ws);
  float* acc    = (float*)(ws + (size_t)524288);
  float* g      = (float*)(ws + (size_t)34078720);
  float* x      = (float*)(ws + (size_t)67633152);
  float* pooled = (float*)(ws + (size_t)101187584);
  float* gout   = (float*)(ws + (size_t)103284736);
  float* W1t    = (float*)(ws + (size_t)115867648);
  unsigned short* pvec = (unsigned short*)(ws + (size_t)524288);  // overlays dead GCN bufs
  float* outp = (float*)d_out;

  k_zerof<<<NN / 256, 256, 0, stream>>>(dinv);
  k_deg<<<EE / 256, 256, 0, stream>>>(ei, dinv);
  k_dinv<<<NN / 256, 256, 0, stream>>>(dinv);
  k_transw<<<(12288 * 32) / 256, 256, 0, stream>>>(l1W, W1t);

  k_mm1<<<NN / 4, 256, 0, stream>>>(drug, g1W, dinv, g);
  k_zero4<<<NN * 64 / 4 / 256, 256, 0, stream>>>((float4*)acc);
  k_edge<<<EE / 4, 256, 0, stream>>>(ei, g, acc);
  k_post<true><<<NN * 64 / 256, 256, 0, stream>>>(acc, g, dinv, g1b, x);

  k_mm2<<<NN / 4, 256, 0, stream>>>(x, g2W, dinv, g);
  k_zero4<<<NN * 64 / 4 / 256, 256, 0, stream>>>((float4*)acc);
  k_edge<<<EE / 4, 256, 0, stream>>>(ei, g, acc);
  k_post<true><<<NN * 64 / 256, 256, 0, stream>>>(acc, g, dinv, g2b, x);

  k_mm2<<<NN / 4, 256, 0, stream>>>(x, g2W, dinv, g);
  k_zero4<<<NN * 64 / 4 / 256, 256, 0, stream>>>((float4*)acc);
  k_edge<<<EE / 4, 256, 0, stream>>>(ei, g, acc);
  k_post<false><<<NN * 64 / 256, 256, 0, stream>>>(acc, g, dinv, g2b, x);

  k_pool<<<BB / 4, 256, 0, stream>>>(x, pooled);
  k_outmm<<<BB / 8, 256, 0, stream>>>(pooled, oW, ob, gout);

  k_cnn<<<BB, 256, 0, stream>>>(gout, protein, c1W, c1b, c2W, c2b, c3W, c3b,
                                caW1, caW2, samW, samb, pvec);

  k_mlp<<<BB / 16, 256, 0, stream>>>(pvec, W1t, l1b, l2W, l2b, l3W, l3b, outp);
}

// Round 4
// 1076.441 us; speedup vs baseline: 2.4118x; 1.2644x over previous
//
#include <hip/hip_runtime.h>
#include <cstdint>
#include <cstddef>

#define NN 131072
#define EE 524288
#define BB 4096
#define LL 768

typedef __attribute__((ext_vector_type(8))) short bf16x8;
typedef __attribute__((ext_vector_type(4))) float f32x4;
typedef __attribute__((ext_vector_type(2))) unsigned int uint2v;
typedef __attribute__((ext_vector_type(4))) unsigned int uint4v;

// ---------- helpers ----------
__device__ __forceinline__ float b2f(unsigned short u) {
  return __uint_as_float(((unsigned int)u) << 16);
}
__device__ __forceinline__ unsigned short f2b(float f) {
  unsigned int x = __float_as_uint(f);
  x += 0x7fff + ((x >> 16) & 1);  // RNE
  return (unsigned short)(x >> 16);
}
__device__ __forceinline__ float sigm(float x) { return 1.f / (1.f + expf(-x)); }
__device__ __forceinline__ float softplus_(float x) {
  return fmaxf(x, 0.f) + log1pf(expf(-fabsf(x)));
}

// ---------- CSR build ----------
__global__ __launch_bounds__(256) void k_zeroi(int* __restrict__ p) {
  p[blockIdx.x * 256 + threadIdx.x] = 0;
}
__global__ __launch_bounds__(256) void k_hist(const int* __restrict__ ei,
                                              int* __restrict__ degi) {
  int e = blockIdx.x * 256 + threadIdx.x;
  atomicAdd(&degi[ei[EE + e]], 1);
}
__global__ __launch_bounds__(256) void k_dinv(const int* __restrict__ degi,
                                              float* __restrict__ d) {
  int i = blockIdx.x * 256 + threadIdx.x;
  d[i] = rsqrtf((float)degi[i] + 1.0f);
}
__global__ __launch_bounds__(256) void k_scan1(const int* __restrict__ degi,
                                               int* __restrict__ incl,
                                               int* __restrict__ bsum) {
  __shared__ int s[256];
  int t = threadIdx.x;
  int i = blockIdx.x * 256 + t;
  s[t] = degi[i];
  __syncthreads();
  for (int off = 1; off < 256; off <<= 1) {
    int u = (t >= off) ? s[t - off] : 0;
    __syncthreads();
    s[t] += u;
    __syncthreads();
  }
  incl[i] = s[t];
  if (t == 255) bsum[blockIdx.x] = s[t];
}
__global__ __launch_bounds__(512) void k_scan2(const int* __restrict__ bsum,
                                               int* __restrict__ bexcl) {
  __shared__ int s[512];
  int t = threadIdx.x;
  s[t] = bsum[t];
  __syncthreads();
  int orig = s[t];
  for (int off = 1; off < 512; off <<= 1) {
    int u = (t >= off) ? s[t - off] : 0;
    __syncthreads();
    s[t] += u;
    __syncthreads();
  }
  bexcl[t] = s[t] - orig;
}
__global__ __launch_bounds__(256) void k_scan3(const int* __restrict__ incl,
                                               const int* __restrict__ degi,
                                               const int* __restrict__ bexcl,
                                               int* __restrict__ offs) {
  int t = threadIdx.x;
  int i = blockIdx.x * 256 + t;
  offs[i] = incl[i] - degi[i] + bexcl[blockIdx.x];
  if (i == 0) offs[NN] = EE;
}
__global__ __launch_bounds__(256) void k_scatter(const int* __restrict__ ei,
                                                 const int* __restrict__ offs,
                                                 int* __restrict__ cur,
                                                 int* __restrict__ csr) {
  int e = blockIdx.x * 256 + threadIdx.x;
  int dst = ei[EE + e];
  int pos = atomicAdd(&cur[dst], 1);
  csr[offs[dst] + pos] = ei[e];
}

// ---------- GCN dense parts ----------
// g[i][f] = dinv[i] * (drug[i,:9] @ W[9,64])[f]
__global__ __launch_bounds__(256) void k_mm1(const float* __restrict__ drug,
                                             const float* __restrict__ W,
                                             const float* __restrict__ dinv,
                                             float* __restrict__ g) {
  __shared__ float Ws[9 * 64];
  int t = threadIdx.x;
  for (int i = t; i < 576; i += 256) Ws[i] = W[i];
  __syncthreads();
  int node = blockIdx.x * 4 + (t >> 6);
  int f = t & 63;
  const float* dr = drug + (size_t)node * 9;
  float s = 0.f;
#pragma unroll
  for (int k = 0; k < 9; k++) s += dr[k] * Ws[k * 64 + f];
  g[(size_t)node * 64 + f] = dinv[node] * s;
}

// CSR pull: x[d] = act(dinv[d]*(sum_{s in N(d)} g[s] + g[d]) + b); optionally
// fused next-layer mm: out[d] = dinv[d]*(x[d] @ W). One wave per node, lane=feature.
template <bool TANH, bool DO_MM>
__global__ __launch_bounds__(256) void k_layer(const float* __restrict__ gin,
                                               const int* __restrict__ offs,
                                               const int* __restrict__ csr,
                                               const float* __restrict__ dinv,
                                               const float* __restrict__ bias,
                                               const float* __restrict__ W,
                                               float* __restrict__ outp) {
  __shared__ float Ws[64 * 64];
  __shared__ float xs[4][64];
  const int t = threadIdx.x;
  if (DO_MM)
    for (int i = t; i < 4096; i += 256) Ws[i] = W[i];
  const int d = blockIdx.x * 4 + (t >> 6);
  const int f = t & 63;
  const float di = dinv[d];
  const int j0 = offs[d], j1 = offs[d + 1];
  float acc = gin[(size_t)d * 64 + f];
  for (int j = j0; j < j1; j++) {
    int s = csr[j];
    acc += gin[(size_t)s * 64 + f];
  }
  float v = di * acc + bias[f];
  if (TANH) v = tanhf(v);
  if (DO_MM) {
    xs[t >> 6][f] = v;
    __syncthreads();
    const float* xr = xs[t >> 6];
    float s = 0.f;
#pragma unroll
    for (int k = 0; k < 64; k++) s += xr[k] * Ws[k * 64 + f];
    outp[(size_t)d * 64 + f] = di * s;
  } else {
    outp[(size_t)d * 64 + f] = v;
  }
}

__global__ __launch_bounds__(256) void k_pool(const float* __restrict__ x,
                                              float* __restrict__ pooled) {
  int t = threadIdx.x;
  int gph = blockIdx.x * 4 + (t >> 6);
  int f = t & 63;
  const float* p = x + (size_t)gph * 32 * 64 + f;
  float mx = -1e30f, sm = 0.f;
#pragma unroll 8
  for (int j = 0; j < 32; j++) {
    float v = p[(size_t)j * 64];
    mx = fmaxf(mx, v);
    sm += v;
  }
  pooled[(size_t)gph * 128 + f] = mx;
  pooled[(size_t)gph * 128 + 64 + f] = sm * (1.f / 32.f);
}

// gout(bf16)[g][o] = pooled[g,:128] @ out_W[128,768] + out_b  (8 graphs / block)
__global__ __launch_bounds__(256) void k_outmm(const float* __restrict__ pooled,
                                               const float* __restrict__ W,
                                               const float* __restrict__ bias,
                                               unsigned short* __restrict__ gout) {
  __shared__ float ps[8][128];
  int t = threadIdx.x;
  int g0 = blockIdx.x * 8;
  for (int i = t; i < 8 * 128; i += 256) ps[i >> 7][i & 127] = pooled[(size_t)g0 * 128 + i];
  __syncthreads();
  float a0[8], a1[8], a2[8];
#pragma unroll
  for (int j = 0; j < 8; j++) { a0[j] = 0.f; a1[j] = 0.f; a2[j] = 0.f; }
  for (int k = 0; k < 128; k++) {
    float w0 = W[k * 768 + t];
    float w1 = W[k * 768 + t + 256];
    float w2 = W[k * 768 + t + 512];
#pragma unroll
    for (int j = 0; j < 8; j++) {
      float p = ps[j][k];
      a0[j] += p * w0; a1[j] += p * w1; a2[j] += p * w2;
    }
  }
  float b0 = bias[t], b1 = bias[t + 256], b2 = bias[t + 512];
  for (int j = 0; j < 8; j++) {
    gout[(size_t)(g0 + j) * 768 + t]       = f2b(a0[j] + b0);
    gout[(size_t)(g0 + j) * 768 + t + 256] = f2b(a1[j] + b1);
    gout[(size_t)(g0 + j) * 768 + t + 512] = f2b(a2[j] + b2);
  }
}

// MFMA conv 32ch->32ch k=3 over position-major bf16 LDS (rows l+1, 32 shorts).
// 8 waves x 6 position-tiles of 16. K tau-major: k = tau*32 + i.
template <bool STATS>
__device__ __forceinline__ void conv_mfma(const unsigned short* in, unsigned short* out,
                                          const unsigned short* Wt, const float* bias,
                                          int t, float tmax[2][4], float tsum[2][4]) {
  const int lane = t & 63, wv = t >> 6;
  const int lx = lane & 15, quad = lane >> 4;
  bf16x8 A[2][3];
  f32x4 cinit[2];
#pragma unroll
  for (int mt = 0; mt < 2; mt++) {
#pragma unroll
    for (int tau = 0; tau < 3; tau++)
      A[mt][tau] = *(const bf16x8*)&Wt[tau * 1024 + (mt * 16 + lx) * 32 + quad * 8];
#pragma unroll
    for (int r = 0; r < 4; r++) cinit[mt][r] = bias[mt * 16 + quad * 4 + r];
  }
  for (int n = 0; n < 6; n++) {
    const int l0 = (wv * 6 + n) * 16;
    bf16x8 Bf[3];
#pragma unroll
    for (int tau = 0; tau < 3; tau++)
      Bf[tau] = *(const bf16x8*)&in[(l0 + lx + tau) * 32 + quad * 8];
#pragma unroll
    for (int mt = 0; mt < 2; mt++) {
      f32x4 acc = cinit[mt];
#pragma unroll
      for (int tau = 0; tau < 3; tau++)
        acc = __builtin_amdgcn_mfma_f32_16x16x32_bf16(A[mt][tau], Bf[tau], acc, 0, 0, 0);
      uint2v pk;
      pk.x = f2b(acc[0]) | ((unsigned)f2b(acc[1]) << 16);
      pk.y = f2b(acc[2]) | ((unsigned)f2b(acc[3]) << 16);
      *(uint2v*)&out[(l0 + lx + 1) * 32 + mt * 16 + quad * 4] = pk;
      if (STATS) {
#pragma unroll
        for (int r = 0; r < 4; r++) {
          tmax[mt][r] = fmaxf(tmax[mt][r], acc[r]);
          tsum[mt][r] += acc[r];
        }
      }
    }
  }
}

// ---------- fully fused CNN chain (512 threads: 8 waves, 2 waves/SIMD) ----------
__global__ __launch_bounds__(512) void k_cnn(
    const unsigned short* __restrict__ gout, const float* __restrict__ protein,
    const float* __restrict__ W1, const float* __restrict__ b1,
    const float* __restrict__ W2, const float* __restrict__ b2,
    const float* __restrict__ W3, const float* __restrict__ b3,
    const float* __restrict__ caW1, const float* __restrict__ caW2,
    const float* __restrict__ samW, const float* __restrict__ samb,
    unsigned short* __restrict__ pvec) {
  __shared__ alignas(16) unsigned short h1t[770 * 32];  // h1, then h3 (rows l+1)
  __shared__ alignas(16) unsigned short h2t[770 * 32];  // comb(f32) -> h2 -> xm/xM/att(f32)
  __shared__ unsigned short W2t[3072], W3t[3072];       // [tau][o][i] bf16
  __shared__ float W1s[192];
  __shared__ float caW1s[512], caW2s[512];
  __shared__ float b1s[32], b2s[32], b3s[32], samWs[8];
  __shared__ float wmaxs[8][32], wsums[8][32];
  __shared__ float cmaxs[32], csums[32], t1buf[2][16], feats[32];
  float* h2f = (float*)h2t;
  const int t = threadIdx.x;
  const int b = blockIdx.x;
  const int lane = t & 63, wv = t >> 6, lx = lane & 15, quad = lane >> 4;

  // ---- S0: stage weights + comb; zero h1t halo rows ----
  for (int i = t; i < 192; i += 512) W1s[i] = W1[i];
  for (int i = t; i < 3072; i += 512) {
    int tau = i >> 10, rem = i & 1023, o = rem >> 5, ic = rem & 31;
    W2t[i] = f2b(W2[o * 96 + ic * 3 + tau]);
    W3t[i] = f2b(W3[o * 96 + ic * 3 + tau]);
  }
  for (int i = t; i < 512; i += 512) { caW1s[i] = caW1[i]; caW2s[i] = caW2[i]; }
  if (t < 32) { b1s[t] = b1[t]; b2s[t] = b2[t]; b3s[t] = b3[t]; }
  if (t >= 64 && t < 70) samWs[t - 64] = samW[t - 64];
  if (t == 70) samWs[6] = samb[0];
  if (t >= 128 && t < 192) {
    int z = t - 128;
    h1t[(z >= 32 ? 769 * 32 : 0) + (z & 31)] = 0;
  }
  for (int i = t; i < 1544; i += 512) {
    int ch = (i >= 772) ? 1 : 0;
    int li = i - ch * 772;
    int l = li - 1;
    float v = 0.f;
    if (l >= 0 && l < LL)
      v = ch ? protein[(size_t)b * LL + l] : b2f(gout[(size_t)b * LL + l]);
    h2f[ch * 772 + li] = v;
  }
  __syncthreads();

  // ---- S1: conv1 (VALU), write position-major h1t ----
  {
    const int oct = t & 3;
    float wr[48], br[8];
#pragma unroll
    for (int a = 0; a < 8; a++) {
      int o = oct * 8 + a;
      br[a] = b1s[o];
#pragma unroll
      for (int q = 0; q < 6; q++) wr[a * 6 + q] = W1s[o * 6 + q];
    }
    const int lbase = t >> 2;  // 0..127
    for (int p = 0; p < 6; p++) {
      int l = lbase + p * 128;
      float c0 = h2f[l], c1 = h2f[l + 1], c2 = h2f[l + 2];
      float d0 = h2f[772 + l], d1 = h2f[772 + l + 1], d2 = h2f[772 + l + 2];
      uint4v pk;
#pragma unroll
      for (int a = 0; a < 4; a++) {
        const float* w0 = &wr[(2 * a) * 6];
        const float* w1 = &wr[(2 * a + 1) * 6];
        float s0 = br[2 * a]     + w0[0] * c0 + w0[1] * c1 + w0[2] * c2
                                 + w0[3] * d0 + w0[4] * d1 + w0[5] * d2;
        float s1 = br[2 * a + 1] + w1[0] * c0 + w1[1] * c1 + w1[2] * c2
                                 + w1[3] * d0 + w1[4] * d1 + w1[5] * d2;
        pk[a] = f2b(s0) | ((unsigned)f2b(s1) << 16);
      }
      *(uint4v*)&h1t[(l + 1) * 32 + oct * 8] = pk;
    }
  }
  __syncthreads();

  // ---- S2: zero h2t halo rows (comb dead) + MFMA conv2: h1t -> h2t ----
  if (t < 64) h2t[(t >= 32 ? 769 * 32 : 0) + (t & 31)] = 0;
  {
    float dm[2][4], ds[2][4];
    conv_mfma<false>(h1t, h2t, W2t, b2s, t, dm, ds);
  }
  __syncthreads();

  // ---- S3: MFMA conv3: h2t -> h1t (=h3), stats in registers ----
  float tmax[2][4], tsum[2][4];
#pragma unroll
  for (int mt = 0; mt < 2; mt++)
#pragma unroll
    for (int r = 0; r < 4; r++) { tmax[mt][r] = -1e30f; tsum[mt][r] = 0.f; }
  conv_mfma<true>(h2t, h1t, W3t, b3s, t, tmax, tsum);
#pragma unroll
  for (int mt = 0; mt < 2; mt++)
#pragma unroll
    for (int r = 0; r < 4; r++) {
      float m = tmax[mt][r], s = tsum[mt][r];
      for (int d = 1; d < 16; d <<= 1) {
        m = fmaxf(m, __shfl_xor(m, d));
        s += __shfl_xor(s, d);
      }
      if (lx == 0) {
        wmaxs[wv][mt * 16 + quad * 4 + r] = m;
        wsums[wv][mt * 16 + quad * 4 + r] = s;
      }
    }
  __syncthreads();

  // ---- S4: cross-wave stats + channel-attention MLP ----
  if (t < 32) {
    float m = wmaxs[0][t], s = wsums[0][t];
#pragma unroll
    for (int w = 1; w < 8; w++) { m = fmaxf(m, wmaxs[w][t]); s += wsums[w][t]; }
    cmaxs[t] = m;
    csums[t] = s;
  }
  __syncthreads();
  if (t < 32) {
    int j = t & 15;
    int mean = t >> 4;
    float s = 0.f;
    for (int o = 0; o < 32; o++) {
      float v = mean ? csums[o] * (1.f / 768.f) : cmaxs[o];
      s += v * caW1s[j * 32 + o];
    }
    t1buf[mean][j] = s;
  }
  __syncthreads();
  if (t < 32) {
    float m1 = 0.f, m2 = 0.f;
    for (int j = 0; j < 16; j++) {
      m1 += t1buf[0][j] * caW2s[t * 16 + j];
      m2 += t1buf[1][j] * caW2s[t * 16 + j];
    }
    feats[t] = sigm(fmaxf(m1, 0.f) + fmaxf(m2, 0.f));
  }
  __syncthreads();

  // ---- S5: spatial stats xm/xM per position (h2t dead -> f32 scratch) ----
  {
    const int oct = t & 3;
    float fr[8];
#pragma unroll
    for (int j = 0; j < 8; j++) fr[j] = feats[oct * 8 + j];
    for (int p = 0; p < 6; p++) {
      int idx = t + p * 512;
      int l = idx >> 2;
      bf16x8 rv = *(const bf16x8*)&h1t[(l + 1) * 32 + oct * 8];
      float sm = 0.f, mx = -1e30f;
#pragma unroll
      for (int j = 0; j < 8; j++) {
        float v = b2f((unsigned short)rv[j]) * fr[j];
        sm += v;
        mx = fmaxf(mx, v);
      }
      sm += __shfl_xor(sm, 1);
      mx = fmaxf(mx, __shfl_xor(mx, 1));
      sm += __shfl_xor(sm, 2);
      mx = fmaxf(mx, __shfl_xor(mx, 2));
      if (oct == 0) {
        h2f[l] = sm * (1.f / 32.f);
        h2f[772 + l] = mx;
      }
    }
  }
  __syncthreads();

  // ---- S6: spatial attention conv + sigmoid ----
  for (int l = t; l < LL; l += 512) {
    float a = samWs[6];
#pragma unroll
    for (int k = 0; k < 3; k++) {
      int ll = l + k - 1;
      float vm = (ll >= 0 && ll < LL) ? h2f[ll] : 0.f;
      float vM = (ll >= 0 && ll < LL) ? h2f[772 + ll] : 0.f;
      a += samWs[k] * vm + samWs[3 + k] * vM;
    }
    h2f[1544 + l] = sigm(a);
  }
  __syncthreads();

  // ---- S7: scale + maxpool2, position-major pvec (coalesced u32 stores) ----
  unsigned* pout = (unsigned*)(pvec + (size_t)b * 12288);
  for (int p = 0; p < 12; p++) {
    int idx = t + p * 512;  // 0..6143
    int ch = (idx & 15) * 2;
    int lp = idx >> 4;
    unsigned a1 = *(const unsigned*)&h1t[(2 * lp + 1) * 32 + ch];
    unsigned a2 = *(const unsigned*)&h1t[(2 * lp + 2) * 32 + ch];
    float f0 = feats[ch], f1 = feats[ch + 1];
    float at0 = h2f[1544 + 2 * lp], at1 = h2f[1544 + 2 * lp + 1];
    float v0 = fmaxf(b2f((unsigned short)(a1 & 0xffff)) * f0 * at0,
                     b2f((unsigned short)(a2 & 0xffff)) * f0 * at1);
    float v1 = fmaxf(b2f((unsigned short)(a1 >> 16)) * f1 * at0,
                     b2f((unsigned short)(a2 >> 16)) * f1 * at1);
    pout[idx] = f2b(v0) | ((unsigned)f2b(v1) << 16);
  }
}

// W1t row p_idx matches pvec layout p_idx = lp*32 + ch  (orig k = ch*384 + lp)
__global__ __launch_bounds__(256) void k_transw(const float* __restrict__ W,
                                                float* __restrict__ Wt) {
  int idx = blockIdx.x * 256 + threadIdx.x;
  int p_idx = idx >> 5, o = idx & 31;
  int ch = p_idx & 31, lp = p_idx >> 5;
  Wt[idx] = W[(size_t)o * 12288 + ch * 384 + lp];
}

// MLP head: 16 graphs/block; W1t streamed once per block as dense float4 rows
__global__ __launch_bounds__(256) void k_mlp(
    const unsigned short* __restrict__ pvec, const float* __restrict__ W1t,
    const float* __restrict__ lb1, const float* __restrict__ W2,
    const float* __restrict__ lb2, const float* __restrict__ W3,
    const float* __restrict__ lb3, float* __restrict__ out) {
  __shared__ float sred[16][16][32];
  __shared__ float s1[16][32];
  __shared__ float s2[16][32];
  const int t = threadIdx.x;
  const int g = t & 15;
  const int ks = t >> 4;
  const size_t gg = (size_t)blockIdx.x * 16 + g;
  const unsigned short* pv = pvec + gg * 12288;
  float acc[32];
#pragma unroll
  for (int o = 0; o < 32; o++) acc[o] = 0.f;
  for (int j = 0; j < 768; j++) {
    int k = ks + 16 * j;
    float v = b2f(pv[k]);
    const float4* w4 = reinterpret_cast<const float4*>(W1t + (size_t)k * 32);
#pragma unroll
    for (int q = 0; q < 8; q++) {
      float4 w = w4[q];
      acc[q * 4 + 0] += v * w.x;
      acc[q * 4 + 1] += v * w.y;
      acc[q * 4 + 2] += v * w.z;
      acc[q * 4 + 3] += v * w.w;
    }
  }
#pragma unroll
  for (int o = 0; o < 32; o++) sred[ks][g][o] = acc[o];
  __syncthreads();
#pragma unroll
  for (int p = 0; p < 2; p++) {
    int idx = t * 2 + p;
    int gi = idx >> 5, o = idx & 31;
    float s = 0.f;
#pragma unroll
    for (int kk = 0; kk < 16; kk++) s += sred[kk][gi][o];
    s1[gi][o] = softplus_(s + lb1[o]);
  }
  __syncthreads();
#pragma unroll
  for (int p = 0; p < 2; p++) {
    int idx = t * 2 + p;
    int gi = idx >> 5, o = idx & 31;
    float s = lb2[o];
    for (int kk = 0; kk < 32; kk++) s += s1[gi][kk] * W2[o * 32 + kk];
    s2[gi][o] = softplus_(s);
  }
  __syncthreads();
  if (t < 16) {
    float s = lb3[0];
    for (int kk = 0; kk < 32; kk++) s += s2[t][kk] * W3[kk];
    out[blockIdx.x * 16 + t] = softplus_(s);
  }
}

extern "C" void kernel_launch(void* const* d_in, const int* in_sizes, int n_in,
                              void* d_out, int out_size, void* d_ws, size_t ws_size,
                              hipStream_t stream) {
  const float* drug    = (const float*)d_in[0];
  const int*   ei      = (const int*)d_in[1];
  const float* protein = (const float*)d_in[3];
  const float* g1W = (const float*)d_in[4];
  const float* g1b = (const float*)d_in[5];
  const float* g2W = (const float*)d_in[6];
  const float* g2b = (const float*)d_in[7];
  const float* oW  = (const float*)d_in[8];
  const float* ob  = (const float*)d_in[9];
  const float* c1W = (const float*)d_in[10];
  const float* c1b = (const float*)d_in[11];
  const float* c2W = (const float*)d_in[12];
  const float* c2b = (const float*)d_in[13];
  const float* c3W = (const float*)d_in[14];
  const float* c3b = (const float*)d_in[15];
  const float* caW1 = (const float*)d_in[16];
  const float* caW2 = (const float*)d_in[17];
  const float* samW = (const float*)d_in[18];
  const float* samb = (const float*)d_in[19];
  const float* l1W = (const float*)d_in[20];
  const float* l1b = (const float*)d_in[21];
  const float* l2W = (const float*)d_in[22];
  const float* l2b = (const float*)d_in[23];
  const float* l3W = (const float*)d_in[24];
  const float* l3b = (const float*)d_in[25];

  // ---- workspace map: peak 110 MiB (< 112 MiB known-safe) ----
  char* ws = (char*)d_ws;
  float* dinv  = (float*)(ws);                       // [0, 0.5M)
  int*   degi  = (int*)(ws + (size_t)524288);        // [0.5M, 1M)
  int*   offs  = (int*)(ws + (size_t)1048576);       // [1M, 1.5M+4)
  int*   cur   = (int*)(ws + (size_t)1576960);       // 0.5M
  int*   bsum  = (int*)(ws + (size_t)2101248);       // 2KB
  int*   bexcl = (int*)(ws + (size_t)2103296);       // 2KB
  int*   csr   = (int*)(ws + (size_t)2359296);       // [2.25M, 4.25M)
  float* gA    = (float*)(ws + (size_t)4718592);     // [4.5M, 36.5M)
  float* gB    = (float*)(ws + (size_t)38273024);    // [36.5M, 68.5M)
  float* x3    = (float*)(ws + (size_t)71827456);    // [68.5M, 100.5M)
  float* pooled= (float*)(ws + (size_t)105381888);   // [100.5M, 102.5M)
  unsigned short* gout = (unsigned short*)(ws + (size_t)107479040);  // [102.5M, 108.5M) bf16
  float* W1t   = (float*)(ws + (size_t)113770496);   // [108.5M, 110M)
  // pvec (96 MiB) overlays gA/gB/x3 — all dead once k_cnn runs
  unsigned short* pvec = (unsigned short*)(ws + (size_t)4718592);
  float* outp = (float*)d_out;

  // ---- CSR build + dinv ----
  k_zeroi<<<NN / 256, 256, 0, stream>>>(degi);
  k_zeroi<<<NN / 256, 256, 0, stream>>>(cur);
  k_hist<<<EE / 256, 256, 0, stream>>>(ei, degi);
  k_dinv<<<NN / 256, 256, 0, stream>>>(degi, dinv);
  k_scan1<<<NN / 256, 256, 0, stream>>>(degi, offs /*incl temp*/, bsum);
  k_scan2<<<1, 512, 0, stream>>>(bsum, bexcl);
  k_scan3<<<NN / 256, 256, 0, stream>>>(offs, degi, bexcl, offs);
  k_scatter<<<EE / 256, 256, 0, stream>>>(ei, offs, cur, csr);
  k_transw<<<(12288 * 32) / 256, 256, 0, stream>>>(l1W, W1t);

  // ---- GCN: g1 = dinv*(drug@W1); then fused aggregate+mm layers ----
  k_mm1<<<NN / 4, 256, 0, stream>>>(drug, g1W, dinv, gA);
  k_layer<true, true><<<NN / 4, 256, 0, stream>>>(gA, offs, csr, dinv, g1b, g2W, gB);
  k_layer<true, true><<<NN / 4, 256, 0, stream>>>(gB, offs, csr, dinv, g2b, g2W, gA);
  k_layer<false, false><<<NN / 4, 256, 0, stream>>>(gA, offs, csr, dinv, g2b, g2W, x3);

  // ---- pool + output linear ----
  k_pool<<<BB / 4, 256, 0, stream>>>(x3, pooled);
  k_outmm<<<BB / 8, 256, 0, stream>>>(pooled, oW, ob, gout);

  // ---- fused CNN chain + CBAM + maxpool ----
  k_cnn<<<BB, 512, 0, stream>>>(gout, protein, c1W, c1b, c2W, c2b, c3W, c3b,
                                caW1, caW2, samW, samb, pvec);

  // ---- MLP head ----
  k_mlp<<<BB / 16, 256, 0, stream>>>(pvec, W1t, l1b, l2W, l2b, l3W, l3b, outp);
}

// Round 5
// 782.683 us; speedup vs baseline: 3.3170x; 1.3753x over previous
//
#include <hip/hip_runtime.h>
#include <cstdint>
#include <cstddef>

#define NN 131072
#define EE 524288
#define BB 4096
#define LL 768

typedef __attribute__((ext_vector_type(8))) short bf16x8;
typedef __attribute__((ext_vector_type(4))) float f32x4;
typedef __attribute__((ext_vector_type(2))) unsigned int uint2v;
typedef __attribute__((ext_vector_type(4))) unsigned int uint4v;

// ---------- helpers ----------
__device__ __forceinline__ float b2f(unsigned short u) {
  return __uint_as_float(((unsigned int)u) << 16);
}
__device__ __forceinline__ unsigned short f2b(float f) {
  unsigned int x = __float_as_uint(f);
  x += 0x7fff + ((x >> 16) & 1);  // RNE
  return (unsigned short)(x >> 16);
}
__device__ __forceinline__ float sigm(float x) { return 1.f / (1.f + expf(-x)); }
__device__ __forceinline__ float softplus_(float x) {
  return fmaxf(x, 0.f) + log1pf(expf(-fabsf(x)));
}

// ---------- CSR build ----------
__global__ __launch_bounds__(256) void k_zeroi(int* __restrict__ p) {
  p[blockIdx.x * 256 + threadIdx.x] = 0;
}
__global__ __launch_bounds__(256) void k_hist(const int* __restrict__ ei,
                                              int* __restrict__ degi) {
  int e = blockIdx.x * 256 + threadIdx.x;
  atomicAdd(&degi[ei[EE + e]], 1);
}
__global__ __launch_bounds__(256) void k_dinv(const int* __restrict__ degi,
                                              float* __restrict__ d) {
  int i = blockIdx.x * 256 + threadIdx.x;
  d[i] = rsqrtf((float)degi[i] + 1.0f);
}
__global__ __launch_bounds__(256) void k_scan1(const int* __restrict__ degi,
                                               int* __restrict__ incl,
                                               int* __restrict__ bsum) {
  __shared__ int s[256];
  int t = threadIdx.x;
  int i = blockIdx.x * 256 + t;
  s[t] = degi[i];
  __syncthreads();
  for (int off = 1; off < 256; off <<= 1) {
    int u = (t >= off) ? s[t - off] : 0;
    __syncthreads();
    s[t] += u;
    __syncthreads();
  }
  incl[i] = s[t];
  if (t == 255) bsum[blockIdx.x] = s[t];
}
__global__ __launch_bounds__(512) void k_scan2(const int* __restrict__ bsum,
                                               int* __restrict__ bexcl) {
  __shared__ int s[512];
  int t = threadIdx.x;
  s[t] = bsum[t];
  __syncthreads();
  int orig = s[t];
  for (int off = 1; off < 512; off <<= 1) {
    int u = (t >= off) ? s[t - off] : 0;
    __syncthreads();
    s[t] += u;
    __syncthreads();
  }
  bexcl[t] = s[t] - orig;
}
__global__ __launch_bounds__(256) void k_scan3(const int* __restrict__ incl,
                                               const int* __restrict__ degi,
                                               const int* __restrict__ bexcl,
                                               int* __restrict__ offs) {
  int t = threadIdx.x;
  int i = blockIdx.x * 256 + t;
  offs[i] = incl[i] - degi[i] + bexcl[blockIdx.x];
  if (i == 0) offs[NN] = EE;
}
__global__ __launch_bounds__(256) void k_scatter(const int* __restrict__ ei,
                                                 const int* __restrict__ offs,
                                                 int* __restrict__ cur,
                                                 int* __restrict__ csr) {
  int e = blockIdx.x * 256 + threadIdx.x;
  int dst = ei[EE + e];
  int pos = atomicAdd(&cur[dst], 1);
  csr[offs[dst] + pos] = ei[e];
}

// ---------- GCN dense parts ----------
__global__ __launch_bounds__(256) void k_mm1(const float* __restrict__ drug,
                                             const float* __restrict__ W,
                                             const float* __restrict__ dinv,
                                             float* __restrict__ g) {
  __shared__ float Ws[9 * 64];
  int t = threadIdx.x;
  for (int i = t; i < 576; i += 256) Ws[i] = W[i];
  __syncthreads();
  int node = blockIdx.x * 4 + (t >> 6);
  int f = t & 63;
  const float* dr = drug + (size_t)node * 9;
  float s = 0.f;
#pragma unroll
  for (int k = 0; k < 9; k++) s += dr[k] * Ws[k * 64 + f];
  g[(size_t)node * 64 + f] = dinv[node] * s;
}

// CSR pull: x[d] = act(dinv[d]*(sum_{s in N(d)} g[s] + g[d]) + b); optional
// fused next-layer mm: out[d] = dinv[d]*(x[d] @ W). One wave per node, lane=feature.
template <bool TANH, bool DO_MM>
__global__ __launch_bounds__(256) void k_layer(const float* __restrict__ gin,
                                               const int* __restrict__ offs,
                                               const int* __restrict__ csr,
                                               const float* __restrict__ dinv,
                                               const float* __restrict__ bias,
                                               const float* __restrict__ W,
                                               float* __restrict__ outp) {
  __shared__ float Ws[64 * 64];
  __shared__ float xs[4][64];
  const int t = threadIdx.x;
  if (DO_MM)
    for (int i = t; i < 4096; i += 256) Ws[i] = W[i];
  const int d = blockIdx.x * 4 + (t >> 6);
  const int f = t & 63;
  const float di = dinv[d];
  const int j0 = offs[d], j1 = offs[d + 1];
  float acc = gin[(size_t)d * 64 + f];
  for (int j = j0; j < j1; j++) {
    int s = csr[j];
    acc += gin[(size_t)s * 64 + f];
  }
  float v = di * acc + bias[f];
  if (TANH) v = tanhf(v);
  if (DO_MM) {
    xs[t >> 6][f] = v;
    __syncthreads();
    const float* xr = xs[t >> 6];
    float s = 0.f;
#pragma unroll
    for (int k = 0; k < 64; k++) s += xr[k] * Ws[k * 64 + f];
    outp[(size_t)d * 64 + f] = di * s;
  } else {
    outp[(size_t)d * 64 + f] = v;
  }
}

__global__ __launch_bounds__(256) void k_pool(const float* __restrict__ x,
                                              float* __restrict__ pooled) {
  int t = threadIdx.x;
  int gph = blockIdx.x * 4 + (t >> 6);
  int f = t & 63;
  const float* p = x + (size_t)gph * 32 * 64 + f;
  float mx = -1e30f, sm = 0.f;
#pragma unroll 8
  for (int j = 0; j < 32; j++) {
    float v = p[(size_t)j * 64];
    mx = fmaxf(mx, v);
    sm += v;
  }
  pooled[(size_t)gph * 128 + f] = mx;
  pooled[(size_t)gph * 128 + 64 + f] = sm * (1.f / 32.f);
}

__global__ __launch_bounds__(256) void k_outmm(const float* __restrict__ pooled,
                                               const float* __restrict__ W,
                                               const float* __restrict__ bias,
                                               unsigned short* __restrict__ gout) {
  __shared__ float ps[8][128];
  int t = threadIdx.x;
  int g0 = blockIdx.x * 8;
  for (int i = t; i < 8 * 128; i += 256) ps[i >> 7][i & 127] = pooled[(size_t)g0 * 128 + i];
  __syncthreads();
  float a0[8], a1[8], a2[8];
#pragma unroll
  for (int j = 0; j < 8; j++) { a0[j] = 0.f; a1[j] = 0.f; a2[j] = 0.f; }
  for (int k = 0; k < 128; k++) {
    float w0 = W[k * 768 + t];
    float w1 = W[k * 768 + t + 256];
    float w2 = W[k * 768 + t + 512];
#pragma unroll
    for (int j = 0; j < 8; j++) {
      float p = ps[j][k];
      a0[j] += p * w0; a1[j] += p * w1; a2[j] += p * w2;
    }
  }
  float b0 = bias[t], b1 = bias[t + 256], b2 = bias[t + 512];
  for (int j = 0; j < 8; j++) {
    gout[(size_t)(g0 + j) * 768 + t]       = f2b(a0[j] + b0);
    gout[(size_t)(g0 + j) * 768 + t + 256] = f2b(a1[j] + b1);
    gout[(size_t)(g0 + j) * 768 + t + 512] = f2b(a2[j] + b2);
  }
}

// MFMA conv 32ch->32ch k=3 over position-major bf16 LDS (rows l+1, 32 shorts).
// 8 waves x 6 position-tiles of 16. K tau-major: k = tau*32 + i.
template <bool STATS>
__device__ __forceinline__ void conv_mfma(const unsigned short* in, unsigned short* out,
                                          const unsigned short* Wt, const float* bias,
                                          int t, float tmax[2][4], float tsum[2][4]) {
  const int lane = t & 63, wv = t >> 6;
  const int lx = lane & 15, quad = lane >> 4;
  bf16x8 A[2][3];
  f32x4 cinit[2];
#pragma unroll
  for (int mt = 0; mt < 2; mt++) {
#pragma unroll
    for (int tau = 0; tau < 3; tau++)
      A[mt][tau] = *(const bf16x8*)&Wt[tau * 1024 + (mt * 16 + lx) * 32 + quad * 8];
#pragma unroll
    for (int r = 0; r < 4; r++) cinit[mt][r] = bias[mt * 16 + quad * 4 + r];
  }
  for (int n = 0; n < 6; n++) {
    const int l0 = (wv * 6 + n) * 16;
    bf16x8 Bf[3];
#pragma unroll
    for (int tau = 0; tau < 3; tau++)
      Bf[tau] = *(const bf16x8*)&in[(l0 + lx + tau) * 32 + quad * 8];
#pragma unroll
    for (int mt = 0; mt < 2; mt++) {
      f32x4 acc = cinit[mt];
#pragma unroll
      for (int tau = 0; tau < 3; tau++)
        acc = __builtin_amdgcn_mfma_f32_16x16x32_bf16(A[mt][tau], Bf[tau], acc, 0, 0, 0);
      uint2v pk;
      pk.x = f2b(acc[0]) | ((unsigned)f2b(acc[1]) << 16);
      pk.y = f2b(acc[2]) | ((unsigned)f2b(acc[3]) << 16);
      *(uint2v*)&out[(l0 + lx + 1) * 32 + mt * 16 + quad * 4] = pk;
      if (STATS) {
#pragma unroll
        for (int r = 0; r < 4; r++) {
          tmax[mt][r] = fmaxf(tmax[mt][r], acc[r]);
          tsum[mt][r] += acc[r];
        }
      }
    }
  }
}

// ---------- fully fused CNN chain (512 threads: 8 waves, 2 waves/SIMD) ----------
__global__ __launch_bounds__(512) void k_cnn(
    const unsigned short* __restrict__ gout, const float* __restrict__ protein,
    const float* __restrict__ W1, const float* __restrict__ b1,
    const float* __restrict__ W2, const float* __restrict__ b2,
    const float* __restrict__ W3, const float* __restrict__ b3,
    const float* __restrict__ caW1, const float* __restrict__ caW2,
    const float* __restrict__ samW, const float* __restrict__ samb,
    unsigned short* __restrict__ pvec) {
  __shared__ alignas(16) unsigned short h1t[770 * 32];  // h1, then h3 (rows l+1)
  __shared__ alignas(16) unsigned short h2t[770 * 32];  // comb(f32) -> h2 -> xm/xM/att(f32)
  __shared__ unsigned short W2t[3072], W3t[3072];       // [tau][o][i] bf16
  __shared__ float W1s[192];
  __shared__ float caW1s[512], caW2s[512];
  __shared__ float b1s[32], b2s[32], b3s[32], samWs[8];
  __shared__ float wmaxs[8][32], wsums[8][32];
  __shared__ float cmaxs[32], csums[32], t1buf[2][16], feats[32];
  float* h2f = (float*)h2t;
  const int t = threadIdx.x;
  const int b = blockIdx.x;
  const int lane = t & 63, wv = t >> 6, lx = lane & 15, quad = lane >> 4;

  // ---- S0: stage weights + comb; zero h1t halo rows ----
  for (int i = t; i < 192; i += 512) W1s[i] = W1[i];
  for (int i = t; i < 3072; i += 512) {
    int tau = i >> 10, rem = i & 1023, o = rem >> 5, ic = rem & 31;
    W2t[i] = f2b(W2[o * 96 + ic * 3 + tau]);
    W3t[i] = f2b(W3[o * 96 + ic * 3 + tau]);
  }
  for (int i = t; i < 512; i += 512) { caW1s[i] = caW1[i]; caW2s[i] = caW2[i]; }
  if (t < 32) { b1s[t] = b1[t]; b2s[t] = b2[t]; b3s[t] = b3[t]; }
  if (t >= 64 && t < 70) samWs[t - 64] = samW[t - 64];
  if (t == 70) samWs[6] = samb[0];
  if (t >= 128 && t < 192) {
    int z = t - 128;
    h1t[(z >= 32 ? 769 * 32 : 0) + (z & 31)] = 0;
  }
  for (int i = t; i < 1544; i += 512) {
    int ch = (i >= 772) ? 1 : 0;
    int li = i - ch * 772;
    int l = li - 1;
    float v = 0.f;
    if (l >= 0 && l < LL)
      v = ch ? protein[(size_t)b * LL + l] : b2f(gout[(size_t)b * LL + l]);
    h2f[ch * 772 + li] = v;
  }
  __syncthreads();

  // ---- S1: conv1 (VALU), write position-major h1t ----
  {
    const int oct = t & 3;
    float wr[48], br[8];
#pragma unroll
    for (int a = 0; a < 8; a++) {
      int o = oct * 8 + a;
      br[a] = b1s[o];
#pragma unroll
      for (int q = 0; q < 6; q++) wr[a * 6 + q] = W1s[o * 6 + q];
    }
    const int lbase = t >> 2;  // 0..127
    for (int p = 0; p < 6; p++) {
      int l = lbase + p * 128;
      float c0 = h2f[l], c1 = h2f[l + 1], c2 = h2f[l + 2];
      float d0 = h2f[772 + l], d1 = h2f[772 + l + 1], d2 = h2f[772 + l + 2];
      uint4v pk;
#pragma unroll
      for (int a = 0; a < 4; a++) {
        const float* w0 = &wr[(2 * a) * 6];
        const float* w1 = &wr[(2 * a + 1) * 6];
        float s0 = br[2 * a]     + w0[0] * c0 + w0[1] * c1 + w0[2] * c2
                                 + w0[3] * d0 + w0[4] * d1 + w0[5] * d2;
        float s1 = br[2 * a + 1] + w1[0] * c0 + w1[1] * c1 + w1[2] * c2
                                 + w1[3] * d0 + w1[4] * d1 + w1[5] * d2;
        pk[a] = f2b(s0) | ((unsigned)f2b(s1) << 16);
      }
      *(uint4v*)&h1t[(l + 1) * 32 + oct * 8] = pk;
    }
  }
  __syncthreads();

  // ---- S2: zero h2t halo rows (comb dead) + MFMA conv2: h1t -> h2t ----
  if (t < 64) h2t[(t >= 32 ? 769 * 32 : 0) + (t & 31)] = 0;
  {
    float dm[2][4], ds[2][4];
    conv_mfma<false>(h1t, h2t, W2t, b2s, t, dm, ds);
  }
  __syncthreads();

  // ---- S3: MFMA conv3: h2t -> h1t (=h3), stats in registers ----
  float tmax[2][4], tsum[2][4];
#pragma unroll
  for (int mt = 0; mt < 2; mt++)
#pragma unroll
    for (int r = 0; r < 4; r++) { tmax[mt][r] = -1e30f; tsum[mt][r] = 0.f; }
  conv_mfma<true>(h2t, h1t, W3t, b3s, t, tmax, tsum);
#pragma unroll
  for (int mt = 0; mt < 2; mt++)
#pragma unroll
    for (int r = 0; r < 4; r++) {
      float m = tmax[mt][r], s = tsum[mt][r];
      for (int d = 1; d < 16; d <<= 1) {
        m = fmaxf(m, __shfl_xor(m, d));
        s += __shfl_xor(s, d);
      }
      if (lx == 0) {
        wmaxs[wv][mt * 16 + quad * 4 + r] = m;
        wsums[wv][mt * 16 + quad * 4 + r] = s;
      }
    }
  __syncthreads();

  // ---- S4: cross-wave stats + channel-attention MLP ----
  if (t < 32) {
    float m = wmaxs[0][t], s = wsums[0][t];
#pragma unroll
    for (int w = 1; w < 8; w++) { m = fmaxf(m, wmaxs[w][t]); s += wsums[w][t]; }
    cmaxs[t] = m;
    csums[t] = s;
  }
  __syncthreads();
  if (t < 32) {
    int j = t & 15;
    int mean = t >> 4;
    float s = 0.f;
    for (int o = 0; o < 32; o++) {
      float v = mean ? csums[o] * (1.f / 768.f) : cmaxs[o];
      s += v * caW1s[j * 32 + o];
    }
    t1buf[mean][j] = s;
  }
  __syncthreads();
  if (t < 32) {
    float m1 = 0.f, m2 = 0.f;
    for (int j = 0; j < 16; j++) {
      m1 += t1buf[0][j] * caW2s[t * 16 + j];
      m2 += t1buf[1][j] * caW2s[t * 16 + j];
    }
    feats[t] = sigm(fmaxf(m1, 0.f) + fmaxf(m2, 0.f));
  }
  __syncthreads();

  // ---- S5: spatial stats xm/xM per position (h2t dead -> f32 scratch) ----
  {
    const int oct = t & 3;
    float fr[8];
#pragma unroll
    for (int j = 0; j < 8; j++) fr[j] = feats[oct * 8 + j];
    for (int p = 0; p < 6; p++) {
      int idx = t + p * 512;
      int l = idx >> 2;
      bf16x8 rv = *(const bf16x8*)&h1t[(l + 1) * 32 + oct * 8];
      float sm = 0.f, mx = -1e30f;
#pragma unroll
      for (int j = 0; j < 8; j++) {
        float v = b2f((unsigned short)rv[j]) * fr[j];
        sm += v;
        mx = fmaxf(mx, v);
      }
      sm += __shfl_xor(sm, 1);
      mx = fmaxf(mx, __shfl_xor(mx, 1));
      sm += __shfl_xor(sm, 2);
      mx = fmaxf(mx, __shfl_xor(mx, 2));
      if (oct == 0) {
        h2f[l] = sm * (1.f / 32.f);
        h2f[772 + l] = mx;
      }
    }
  }
  __syncthreads();

  // ---- S6: spatial attention conv + sigmoid ----
  for (int l = t; l < LL; l += 512) {
    float a = samWs[6];
#pragma unroll
    for (int k = 0; k < 3; k++) {
      int ll = l + k - 1;
      float vm = (ll >= 0 && ll < LL) ? h2f[ll] : 0.f;
      float vM = (ll >= 0 && ll < LL) ? h2f[772 + ll] : 0.f;
      a += samWs[k] * vm + samWs[3 + k] * vM;
    }
    h2f[1544 + l] = sigm(a);
  }
  __syncthreads();

  // ---- S7: scale + maxpool2, position-major pvec (coalesced u32 stores) ----
  unsigned* pout = (unsigned*)(pvec + (size_t)b * 12288);
  for (int p = 0; p < 12; p++) {
    int idx = t + p * 512;  // 0..6143
    int ch = (idx & 15) * 2;
    int lp = idx >> 4;
    unsigned a1 = *(const unsigned*)&h1t[(2 * lp + 1) * 32 + ch];
    unsigned a2 = *(const unsigned*)&h1t[(2 * lp + 2) * 32 + ch];
    float f0 = feats[ch], f1 = feats[ch + 1];
    float at0 = h2f[1544 + 2 * lp], at1 = h2f[1544 + 2 * lp + 1];
    float v0 = fmaxf(b2f((unsigned short)(a1 & 0xffff)) * f0 * at0,
                     b2f((unsigned short)(a2 & 0xffff)) * f0 * at1);
    float v1 = fmaxf(b2f((unsigned short)(a1 >> 16)) * f1 * at0,
                     b2f((unsigned short)(a2 >> 16)) * f1 * at1);
    pout[idx] = f2b(v0) | ((unsigned)f2b(v1) << 16);
  }
}

// Wb in MFMA B-fragment order, bf16: Wb[((kt*2+nt)*64+lane)*8+j] = W1[o][korig]
// with o = nt*16+(lane&15), k = kt*32+(lane>>4)*8+j (pvec index), korig = (k&31)*384+(k>>5)
__global__ __launch_bounds__(256) void k_prepw(const float* __restrict__ W,
                                               unsigned short* __restrict__ Wb) {
  int idx = blockIdx.x * 256 + threadIdx.x;  // 0 .. 393215
  int j = idx & 7;
  int lane = (idx >> 3) & 63;
  int nt = (idx >> 9) & 1;
  int kt = idx >> 10;
  int o = nt * 16 + (lane & 15);
  int k = kt * 32 + (lane >> 4) * 8 + j;
  int korig = (k & 31) * 384 + (k >> 5);
  Wb[idx] = f2b(W[(size_t)o * 12288 + korig]);
}

// MFMA MLP head: block = 16 graphs, 8 waves; wave = K-chunk of 1536 (48 tiles).
// Then LDS reduce + bias + softplus + layers 2,3 in-block.
__global__ __launch_bounds__(512) void k_mlp(
    const unsigned short* __restrict__ pvec, const unsigned short* __restrict__ Wb,
    const float* __restrict__ lb1, const float* __restrict__ W2,
    const float* __restrict__ lb2, const float* __restrict__ W3,
    const float* __restrict__ lb3, float* __restrict__ out) {
  __shared__ float part[8][16][32];
  __shared__ float s1[16][32];
  __shared__ float s2[16][32];
  const int t = threadIdx.x;
  const int lane = t & 63, wv = t >> 6, lx = lane & 15, quad = lane >> 4;
  const int g0 = blockIdx.x * 16;
  const unsigned short* arow = pvec + (size_t)(g0 + lx) * 12288 + quad * 8;

  f32x4 acc0 = {0.f, 0.f, 0.f, 0.f}, acc1 = {0.f, 0.f, 0.f, 0.f};
  const int kt0 = wv * 48;
#pragma unroll 4
  for (int i = 0; i < 48; i++) {
    const int kt = kt0 + i;
    bf16x8 A = *(const bf16x8*)&arow[kt * 32];
    bf16x8 B0 = *(const bf16x8*)&Wb[((kt * 2 + 0) * 64 + lane) * 8];
    bf16x8 B1 = *(const bf16x8*)&Wb[((kt * 2 + 1) * 64 + lane) * 8];
    acc0 = __builtin_amdgcn_mfma_f32_16x16x32_bf16(A, B0, acc0, 0, 0, 0);
    acc1 = __builtin_amdgcn_mfma_f32_16x16x32_bf16(A, B1, acc1, 0, 0, 0);
  }
  // D layout: col(n)=lane&15, row(m)=quad*4+r
#pragma unroll
  for (int r = 0; r < 4; r++) {
    part[wv][quad * 4 + r][lx] = acc0[r];
    part[wv][quad * 4 + r][16 + lx] = acc1[r];
  }
  __syncthreads();
  // reduce 8 partials + bias + softplus -> s1[g][o]   (512 elems, 1/thread)
  {
    int g = t >> 5, o = t & 31;
    float s = 0.f;
#pragma unroll
    for (int w = 0; w < 8; w++) s += part[w][g][o];
    s1[g][o] = softplus_(s + lb1[o]);
  }
  __syncthreads();
  // layer 2
  {
    int g = t >> 5, o = t & 31;
    float s = lb2[o];
    for (int kk = 0; kk < 32; kk++) s += s1[g][kk] * W2[o * 32 + kk];
    s2[g][o] = softplus_(s);
  }
  __syncthreads();
  // layer 3
  if (t < 16) {
    float s = lb3[0];
    for (int kk = 0; kk < 32; kk++) s += s2[t][kk] * W3[kk];
    out[g0 + t] = softplus_(s);
  }
}

extern "C" void kernel_launch(void* const* d_in, const int* in_sizes, int n_in,
                              void* d_out, int out_size, void* d_ws, size_t ws_size,
                              hipStream_t stream) {
  const float* drug    = (const float*)d_in[0];
  const int*   ei      = (const int*)d_in[1];
  const float* protein = (const float*)d_in[3];
  const float* g1W = (const float*)d_in[4];
  const float* g1b = (const float*)d_in[5];
  const float* g2W = (const float*)d_in[6];
  const float* g2b = (const float*)d_in[7];
  const float* oW  = (const float*)d_in[8];
  const float* ob  = (const float*)d_in[9];
  const float* c1W = (const float*)d_in[10];
  const float* c1b = (const float*)d_in[11];
  const float* c2W = (const float*)d_in[12];
  const float* c2b = (const float*)d_in[13];
  const float* c3W = (const float*)d_in[14];
  const float* c3b = (const float*)d_in[15];
  const float* caW1 = (const float*)d_in[16];
  const float* caW2 = (const float*)d_in[17];
  const float* samW = (const float*)d_in[18];
  const float* samb = (const float*)d_in[19];
  const float* l1W = (const float*)d_in[20];
  const float* l1b = (const float*)d_in[21];
  const float* l2W = (const float*)d_in[22];
  const float* l2b = (const float*)d_in[23];
  const float* l3W = (const float*)d_in[24];
  const float* l3b = (const float*)d_in[25];

  // ---- workspace map: peak 110 MiB (< 112 MiB known-safe) ----
  char* ws = (char*)d_ws;
  float* dinv  = (float*)(ws);                       // [0, 0.5M)
  int*   degi  = (int*)(ws + (size_t)524288);        // [0.5M, 1M)
  int*   offs  = (int*)(ws + (size_t)1048576);       // [1M, 1.5M+4)
  int*   cur   = (int*)(ws + (size_t)1576960);       // 0.5M
  int*   bsum  = (int*)(ws + (size_t)2101248);       // 2KB
  int*   bexcl = (int*)(ws + (size_t)2103296);       // 2KB
  int*   csr   = (int*)(ws + (size_t)2359296);       // [2.25M, 4.25M)
  float* gA    = (float*)(ws + (size_t)4718592);     // [4.5M, 36.5M)
  float* gB    = (float*)(ws + (size_t)38273024);    // [36.5M, 68.5M)
  float* x3    = (float*)(ws + (size_t)71827456);    // [68.5M, 100.5M)
  float* pooled= (float*)(ws + (size_t)105381888);   // [100.5M, 102.5M)
  unsigned short* gout = (unsigned short*)(ws + (size_t)107479040);  // [102.5M, 108.5M) bf16
  unsigned short* Wb   = (unsigned short*)(ws + (size_t)113770496);  // [108.5M, 109.25M) bf16
  // pvec (96 MiB) overlays gA/gB/x3 — all dead once k_cnn runs
  unsigned short* pvec = (unsigned short*)(ws + (size_t)4718592);
  float* outp = (float*)d_out;

  // ---- CSR build + dinv ----
  k_zeroi<<<NN / 256, 256, 0, stream>>>(degi);
  k_zeroi<<<NN / 256, 256, 0, stream>>>(cur);
  k_hist<<<EE / 256, 256, 0, stream>>>(ei, degi);
  k_dinv<<<NN / 256, 256, 0, stream>>>(degi, dinv);
  k_scan1<<<NN / 256, 256, 0, stream>>>(degi, offs /*incl temp*/, bsum);
  k_scan2<<<1, 512, 0, stream>>>(bsum, bexcl);
  k_scan3<<<NN / 256, 256, 0, stream>>>(offs, degi, bexcl, offs);
  k_scatter<<<EE / 256, 256, 0, stream>>>(ei, offs, cur, csr);
  k_prepw<<<(12288 * 32) / 256, 256, 0, stream>>>(l1W, Wb);

  // ---- GCN: g1 = dinv*(drug@W1); then fused aggregate+mm layers ----
  k_mm1<<<NN / 4, 256, 0, stream>>>(drug, g1W, dinv, gA);
  k_layer<true, true><<<NN / 4, 256, 0, stream>>>(gA, offs, csr, dinv, g1b, g2W, gB);
  k_layer<true, true><<<NN / 4, 256, 0, stream>>>(gB, offs, csr, dinv, g2b, g2W, gA);
  k_layer<false, false><<<NN / 4, 256, 0, stream>>>(gA, offs, csr, dinv, g2b, g2W, x3);

  // ---- pool + output linear ----
  k_pool<<<BB / 4, 256, 0, stream>>>(x3, pooled);
  k_outmm<<<BB / 8, 256, 0, stream>>>(pooled, oW, ob, gout);

  // ---- fused CNN chain + CBAM + maxpool ----
  k_cnn<<<BB, 512, 0, stream>>>(gout, protein, c1W, c1b, c2W, c2b, c3W, c3b,
                                caW1, caW2, samW, samb, pvec);

  // ---- MLP head (MFMA) ----
  k_mlp<<<BB / 16, 512, 0, stream>>>(pvec, Wb, l1b, l2W, l2b, l3W, l3b, outp);
}

// Round 6
// 762.085 us; speedup vs baseline: 3.4067x; 1.0270x over previous
//
#include <hip/hip_runtime.h>
#include <cstdint>
#include <cstddef>

#define NN 131072
#define EE 524288
#define BB 4096
#define LL 768

typedef __attribute__((ext_vector_type(8))) short bf16x8;
typedef __attribute__((ext_vector_type(4))) float f32x4;
typedef __attribute__((ext_vector_type(2))) unsigned int uint2v;
typedef __attribute__((ext_vector_type(4))) unsigned int uint4v;

// ---------- helpers ----------
__device__ __forceinline__ float b2f(unsigned short u) {
  return __uint_as_float(((unsigned int)u) << 16);
}
__device__ __forceinline__ unsigned short f2b(float f) {
  unsigned int x = __float_as_uint(f);
  x += 0x7fff + ((x >> 16) & 1);  // RNE
  return (unsigned short)(x >> 16);
}
__device__ __forceinline__ float sigm(float x) { return 1.f / (1.f + expf(-x)); }
__device__ __forceinline__ float softplus_(float x) {
  return fmaxf(x, 0.f) + log1pf(expf(-fabsf(x)));
}

// ---------- CSR build ----------
__global__ __launch_bounds__(256) void k_zeroi(int* __restrict__ p) {
  p[blockIdx.x * 256 + threadIdx.x] = 0;
}
__global__ __launch_bounds__(256) void k_hist(const int* __restrict__ ei,
                                              int* __restrict__ degi) {
  int e = blockIdx.x * 256 + threadIdx.x;
  atomicAdd(&degi[ei[EE + e]], 1);
}
__global__ __launch_bounds__(256) void k_dinv(const int* __restrict__ degi,
                                              float* __restrict__ d) {
  int i = blockIdx.x * 256 + threadIdx.x;
  d[i] = rsqrtf((float)degi[i] + 1.0f);
}
__global__ __launch_bounds__(256) void k_scan1(const int* __restrict__ degi,
                                               int* __restrict__ incl,
                                               int* __restrict__ bsum) {
  __shared__ int s[256];
  int t = threadIdx.x;
  int i = blockIdx.x * 256 + t;
  s[t] = degi[i];
  __syncthreads();
  for (int off = 1; off < 256; off <<= 1) {
    int u = (t >= off) ? s[t - off] : 0;
    __syncthreads();
    s[t] += u;
    __syncthreads();
  }
  incl[i] = s[t];
  if (t == 255) bsum[blockIdx.x] = s[t];
}
__global__ __launch_bounds__(512) void k_scan2(const int* __restrict__ bsum,
                                               int* __restrict__ bexcl) {
  __shared__ int s[512];
  int t = threadIdx.x;
  s[t] = bsum[t];
  __syncthreads();
  int orig = s[t];
  for (int off = 1; off < 512; off <<= 1) {
    int u = (t >= off) ? s[t - off] : 0;
    __syncthreads();
    s[t] += u;
    __syncthreads();
  }
  bexcl[t] = s[t] - orig;
}
__global__ __launch_bounds__(256) void k_scan3(const int* __restrict__ incl,
                                               const int* __restrict__ degi,
                                               const int* __restrict__ bexcl,
                                               int* __restrict__ offs) {
  int t = threadIdx.x;
  int i = blockIdx.x * 256 + t;
  offs[i] = incl[i] - degi[i] + bexcl[blockIdx.x];
  if (i == 0) offs[NN] = EE;
}
__global__ __launch_bounds__(256) void k_scatter(const int* __restrict__ ei,
                                                 const int* __restrict__ offs,
                                                 int* __restrict__ cur,
                                                 int* __restrict__ csr) {
  int e = blockIdx.x * 256 + threadIdx.x;
  int dst = ei[EE + e];
  int pos = atomicAdd(&cur[dst], 1);
  csr[offs[dst] + pos] = ei[e];
}

// ---------- GCN dense parts (g buffers in bf16) ----------
__global__ __launch_bounds__(256) void k_mm1(const float* __restrict__ drug,
                                             const float* __restrict__ W,
                                             const float* __restrict__ dinv,
                                             unsigned short* __restrict__ g) {
  __shared__ float Ws[9 * 64];
  int t = threadIdx.x;
  for (int i = t; i < 576; i += 256) Ws[i] = W[i];
  __syncthreads();
  int node = blockIdx.x * 4 + (t >> 6);
  int f = t & 63;
  const float* dr = drug + (size_t)node * 9;
  float s = 0.f;
#pragma unroll
  for (int k = 0; k < 9; k++) s += dr[k] * Ws[k * 64 + f];
  g[(size_t)node * 64 + f] = f2b(dinv[node] * s);
}

// CSR pull (bf16 gather, 4-way unrolled for ILP): x[d] = act(dinv*(sum g[s] + g[d]) + b);
// optional fused next-layer mm -> bf16 out; else fp32 out.
template <bool TANH, bool DO_MM>
__global__ __launch_bounds__(256) void k_layer(const unsigned short* __restrict__ gin,
                                               const int* __restrict__ offs,
                                               const int* __restrict__ csr,
                                               const float* __restrict__ dinv,
                                               const float* __restrict__ bias,
                                               const float* __restrict__ W,
                                               unsigned short* __restrict__ outb,
                                               float* __restrict__ outf) {
  __shared__ float Ws[64 * 64];
  __shared__ float xs[4][64];
  const int t = threadIdx.x;
  if (DO_MM)
    for (int i = t; i < 4096; i += 256) Ws[i] = W[i];
  const int d = blockIdx.x * 4 + (t >> 6);
  const int f = t & 63;
  const float di = dinv[d];
  const int j0 = offs[d], j1 = offs[d + 1];
  float acc = b2f(gin[(size_t)d * 64 + f]);
  int j = j0;
  for (; j + 4 <= j1; j += 4) {
    int s0 = csr[j], s1 = csr[j + 1], s2 = csr[j + 2], s3 = csr[j + 3];
    float v0 = b2f(gin[(size_t)s0 * 64 + f]);
    float v1 = b2f(gin[(size_t)s1 * 64 + f]);
    float v2 = b2f(gin[(size_t)s2 * 64 + f]);
    float v3 = b2f(gin[(size_t)s3 * 64 + f]);
    acc += (v0 + v1) + (v2 + v3);
  }
  for (; j < j1; j++) acc += b2f(gin[(size_t)csr[j] * 64 + f]);
  float v = di * acc + bias[f];
  if (TANH) v = tanhf(v);
  if (DO_MM) {
    xs[t >> 6][f] = v;
    __syncthreads();
    const float* xr = xs[t >> 6];
    float s = 0.f;
#pragma unroll
    for (int k = 0; k < 64; k++) s += xr[k] * Ws[k * 64 + f];
    outb[(size_t)d * 64 + f] = f2b(di * s);
  } else {
    outf[(size_t)d * 64 + f] = v;
  }
}

__global__ __launch_bounds__(256) void k_pool(const float* __restrict__ x,
                                              float* __restrict__ pooled) {
  int t = threadIdx.x;
  int gph = blockIdx.x * 4 + (t >> 6);
  int f = t & 63;
  const float* p = x + (size_t)gph * 32 * 64 + f;
  float mx = -1e30f, sm = 0.f;
#pragma unroll 8
  for (int j = 0; j < 32; j++) {
    float v = p[(size_t)j * 64];
    mx = fmaxf(mx, v);
    sm += v;
  }
  pooled[(size_t)gph * 128 + f] = mx;
  pooled[(size_t)gph * 128 + 64 + f] = sm * (1.f / 32.f);
}

// gout(bf16): 16 graphs/block (halves out_W re-reads vs 8/block)
__global__ __launch_bounds__(256) void k_outmm(const float* __restrict__ pooled,
                                               const float* __restrict__ W,
                                               const float* __restrict__ bias,
                                               unsigned short* __restrict__ gout) {
  __shared__ float ps[16][128];
  int t = threadIdx.x;
  int g0 = blockIdx.x * 16;
  for (int i = t; i < 16 * 128; i += 256) ps[i >> 7][i & 127] = pooled[(size_t)g0 * 128 + i];
  __syncthreads();
  float a0[16], a1[16], a2[16];
#pragma unroll
  for (int j = 0; j < 16; j++) { a0[j] = 0.f; a1[j] = 0.f; a2[j] = 0.f; }
  for (int k = 0; k < 128; k++) {
    float w0 = W[k * 768 + t];
    float w1 = W[k * 768 + t + 256];
    float w2 = W[k * 768 + t + 512];
#pragma unroll
    for (int j = 0; j < 16; j++) {
      float p = ps[j][k];
      a0[j] += p * w0; a1[j] += p * w1; a2[j] += p * w2;
    }
  }
  float b0 = bias[t], b1 = bias[t + 256], b2 = bias[t + 512];
  for (int j = 0; j < 16; j++) {
    gout[(size_t)(g0 + j) * 768 + t]       = f2b(a0[j] + b0);
    gout[(size_t)(g0 + j) * 768 + t + 256] = f2b(a1[j] + b1);
    gout[(size_t)(g0 + j) * 768 + t + 512] = f2b(a2[j] + b2);
  }
}

// MFMA conv 32ch->32ch k=3 over position-major bf16 LDS (rows l+1, 32 shorts).
// 16 waves x 3 position-tiles of 16. K tau-major: k = tau*32 + i.
template <bool STATS>
__device__ __forceinline__ void conv_mfma(const unsigned short* in, unsigned short* out,
                                          const unsigned short* Wt, const float* bias,
                                          int t, float tmax[2][4], float tsum[2][4]) {
  const int lane = t & 63, wv = t >> 6;
  const int lx = lane & 15, quad = lane >> 4;
  bf16x8 A[2][3];
  f32x4 cinit[2];
#pragma unroll
  for (int mt = 0; mt < 2; mt++) {
#pragma unroll
    for (int tau = 0; tau < 3; tau++)
      A[mt][tau] = *(const bf16x8*)&Wt[tau * 1024 + (mt * 16 + lx) * 32 + quad * 8];
#pragma unroll
    for (int r = 0; r < 4; r++) cinit[mt][r] = bias[mt * 16 + quad * 4 + r];
  }
#pragma unroll
  for (int n = 0; n < 3; n++) {
    const int l0 = (wv * 3 + n) * 16;
    bf16x8 Bf[3];
#pragma unroll
    for (int tau = 0; tau < 3; tau++)
      Bf[tau] = *(const bf16x8*)&in[(l0 + lx + tau) * 32 + quad * 8];
#pragma unroll
    for (int mt = 0; mt < 2; mt++) {
      f32x4 acc = cinit[mt];
#pragma unroll
      for (int tau = 0; tau < 3; tau++)
        acc = __builtin_amdgcn_mfma_f32_16x16x32_bf16(A[mt][tau], Bf[tau], acc, 0, 0, 0);
      uint2v pk;
      pk.x = f2b(acc[0]) | ((unsigned)f2b(acc[1]) << 16);
      pk.y = f2b(acc[2]) | ((unsigned)f2b(acc[3]) << 16);
      *(uint2v*)&out[(l0 + lx + 1) * 32 + mt * 16 + quad * 4] = pk;
      if (STATS) {
#pragma unroll
        for (int r = 0; r < 4; r++) {
          tmax[mt][r] = fmaxf(tmax[mt][r], acc[r]);
          tsum[mt][r] += acc[r];
        }
      }
    }
  }
}

// ---------- fully fused CNN chain (1024 threads: 16 waves, 4 waves/SIMD) ----------
__global__ __launch_bounds__(1024) void k_cnn(
    const unsigned short* __restrict__ gout, const float* __restrict__ protein,
    const float* __restrict__ W1, const float* __restrict__ b1,
    const float* __restrict__ W2, const float* __restrict__ b2,
    const float* __restrict__ W3, const float* __restrict__ b3,
    const float* __restrict__ caW1, const float* __restrict__ caW2,
    const float* __restrict__ samW, const float* __restrict__ samb,
    unsigned short* __restrict__ pvec) {
  __shared__ alignas(16) unsigned short h1t[770 * 32];  // h1, then h3 (rows l+1)
  __shared__ alignas(16) unsigned short h2t[770 * 32];  // comb(f32) -> h2 -> xm/xM/att(f32)
  __shared__ unsigned short W2t[3072], W3t[3072];       // [tau][o][i] bf16
  __shared__ float W1s[192];
  __shared__ float caW1s[512], caW2s[512];
  __shared__ float b1s[32], b2s[32], b3s[32], samWs[8];
  __shared__ float wmaxs[16][32], wsums[16][32];
  __shared__ float cmaxs[32], csums[32], t1buf[2][16], feats[32];
  float* h2f = (float*)h2t;
  const int t = threadIdx.x;
  const int b = blockIdx.x;
  const int lane = t & 63, wv = t >> 6, lx = lane & 15, quad = lane >> 4;

  // ---- S0: stage weights + comb; zero h1t halo rows ----
  if (t < 192) W1s[t] = W1[t];
  for (int i = t; i < 3072; i += 1024) {
    int tau = i >> 10, rem = i & 1023, o = rem >> 5, ic = rem & 31;
    W2t[i] = f2b(W2[o * 96 + ic * 3 + tau]);
    W3t[i] = f2b(W3[o * 96 + ic * 3 + tau]);
  }
  if (t < 512) { caW1s[t] = caW1[t]; caW2s[t] = caW2[t]; }
  if (t >= 512 && t < 544) {
    int i = t - 512;
    b1s[i] = b1[i]; b2s[i] = b2[i]; b3s[i] = b3[i];
  }
  if (t >= 576 && t < 582) samWs[t - 576] = samW[t - 576];
  if (t == 582) samWs[6] = samb[0];
  if (t >= 640 && t < 704) {
    int z = t - 640;
    h1t[(z >= 32 ? 769 * 32 : 0) + (z & 31)] = 0;
  }
  for (int i = t; i < 1544; i += 1024) {
    int ch = (i >= 772) ? 1 : 0;
    int li = i - ch * 772;
    int l = li - 1;
    float v = 0.f;
    if (l >= 0 && l < LL)
      v = ch ? protein[(size_t)b * LL + l] : b2f(gout[(size_t)b * LL + l]);
    h2f[ch * 772 + li] = v;
  }
  __syncthreads();

  // ---- S1: conv1 (VALU), write position-major h1t ----
  {
    const int oct = t & 3;
    float wr[48], br[8];
#pragma unroll
    for (int a = 0; a < 8; a++) {
      int o = oct * 8 + a;
      br[a] = b1s[o];
#pragma unroll
      for (int q = 0; q < 6; q++) wr[a * 6 + q] = W1s[o * 6 + q];
    }
    const int lbase = t >> 2;  // 0..255
#pragma unroll
    for (int p = 0; p < 3; p++) {
      int l = lbase + p * 256;
      float c0 = h2f[l], c1 = h2f[l + 1], c2 = h2f[l + 2];
      float d0 = h2f[772 + l], d1 = h2f[772 + l + 1], d2 = h2f[772 + l + 2];
      uint4v pk;
#pragma unroll
      for (int a = 0; a < 4; a++) {
        const float* w0 = &wr[(2 * a) * 6];
        const float* w1 = &wr[(2 * a + 1) * 6];
        float s0 = br[2 * a]     + w0[0] * c0 + w0[1] * c1 + w0[2] * c2
                                 + w0[3] * d0 + w0[4] * d1 + w0[5] * d2;
        float s1 = br[2 * a + 1] + w1[0] * c0 + w1[1] * c1 + w1[2] * c2
                                 + w1[3] * d0 + w1[4] * d1 + w1[5] * d2;
        pk[a] = f2b(s0) | ((unsigned)f2b(s1) << 16);
      }
      *(uint4v*)&h1t[(l + 1) * 32 + oct * 8] = pk;
    }
  }
  __syncthreads();

  // ---- S2: zero h2t halo rows (comb dead) + MFMA conv2: h1t -> h2t ----
  if (t < 64) h2t[(t >= 32 ? 769 * 32 : 0) + (t & 31)] = 0;
  {
    float dm[2][4], ds[2][4];
    conv_mfma<false>(h1t, h2t, W2t, b2s, t, dm, ds);
  }
  __syncthreads();

  // ---- S3: MFMA conv3: h2t -> h1t (=h3), stats in registers ----
  float tmax[2][4], tsum[2][4];
#pragma unroll
  for (int mt = 0; mt < 2; mt++)
#pragma unroll
    for (int r = 0; r < 4; r++) { tmax[mt][r] = -1e30f; tsum[mt][r] = 0.f; }
  conv_mfma<true>(h2t, h1t, W3t, b3s, t, tmax, tsum);
#pragma unroll
  for (int mt = 0; mt < 2; mt++)
#pragma unroll
    for (int r = 0; r < 4; r++) {
      float m = tmax[mt][r], s = tsum[mt][r];
      for (int d = 1; d < 16; d <<= 1) {
        m = fmaxf(m, __shfl_xor(m, d));
        s += __shfl_xor(s, d);
      }
      if (lx == 0) {
        wmaxs[wv][mt * 16 + quad * 4 + r] = m;
        wsums[wv][mt * 16 + quad * 4 + r] = s;
      }
    }
  __syncthreads();

  // ---- S4: cross-wave stats + channel-attention MLP ----
  if (t < 32) {
    float m = wmaxs[0][t], s = wsums[0][t];
#pragma unroll
    for (int w = 1; w < 16; w++) { m = fmaxf(m, wmaxs[w][t]); s += wsums[w][t]; }
    cmaxs[t] = m;
    csums[t] = s;
  }
  __syncthreads();
  if (t < 32) {
    int j = t & 15;
    int mean = t >> 4;
    float s = 0.f;
    for (int o = 0; o < 32; o++) {
      float v = mean ? csums[o] * (1.f / 768.f) : cmaxs[o];
      s += v * caW1s[j * 32 + o];
    }
    t1buf[mean][j] = s;
  }
  __syncthreads();
  if (t < 32) {
    float m1 = 0.f, m2 = 0.f;
    for (int j = 0; j < 16; j++) {
      m1 += t1buf[0][j] * caW2s[t * 16 + j];
      m2 += t1buf[1][j] * caW2s[t * 16 + j];
    }
    feats[t] = sigm(fmaxf(m1, 0.f) + fmaxf(m2, 0.f));
  }
  __syncthreads();

  // ---- S5: spatial stats xm/xM per position (h2t dead -> f32 scratch) ----
  {
    const int oct = t & 3;
    float fr[8];
#pragma unroll
    for (int j = 0; j < 8; j++) fr[j] = feats[oct * 8 + j];
#pragma unroll
    for (int p = 0; p < 3; p++) {
      int idx = t + p * 1024;
      int l = idx >> 2;
      bf16x8 rv = *(const bf16x8*)&h1t[(l + 1) * 32 + oct * 8];
      float sm = 0.f, mx = -1e30f;
#pragma unroll
      for (int j = 0; j < 8; j++) {
        float v = b2f((unsigned short)rv[j]) * fr[j];
        sm += v;
        mx = fmaxf(mx, v);
      }
      sm += __shfl_xor(sm, 1);
      mx = fmaxf(mx, __shfl_xor(mx, 1));
      sm += __shfl_xor(sm, 2);
      mx = fmaxf(mx, __shfl_xor(mx, 2));
      if (oct == 0) {
        h2f[l] = sm * (1.f / 32.f);
        h2f[772 + l] = mx;
      }
    }
  }
  __syncthreads();

  // ---- S6: spatial attention conv + sigmoid ----
  if (t < LL) {
    int l = t;
    float a = samWs[6];
#pragma unroll
    for (int k = 0; k < 3; k++) {
      int ll = l + k - 1;
      float vm = (ll >= 0 && ll < LL) ? h2f[ll] : 0.f;
      float vM = (ll >= 0 && ll < LL) ? h2f[772 + ll] : 0.f;
      a += samWs[k] * vm + samWs[3 + k] * vM;
    }
    h2f[1544 + l] = sigm(a);
  }
  __syncthreads();

  // ---- S7: scale + maxpool2, position-major pvec (coalesced u32 stores) ----
  unsigned* pout = (unsigned*)(pvec + (size_t)b * 12288);
#pragma unroll
  for (int p = 0; p < 6; p++) {
    int idx = t + p * 1024;  // 0..6143
    int ch = (idx & 15) * 2;
    int lp = idx >> 4;
    unsigned a1 = *(const unsigned*)&h1t[(2 * lp + 1) * 32 + ch];
    unsigned a2 = *(const unsigned*)&h1t[(2 * lp + 2) * 32 + ch];
    float f0 = feats[ch], f1 = feats[ch + 1];
    float at0 = h2f[1544 + 2 * lp], at1 = h2f[1544 + 2 * lp + 1];
    float v0 = fmaxf(b2f((unsigned short)(a1 & 0xffff)) * f0 * at0,
                     b2f((unsigned short)(a2 & 0xffff)) * f0 * at1);
    float v1 = fmaxf(b2f((unsigned short)(a1 >> 16)) * f1 * at0,
                     b2f((unsigned short)(a2 >> 16)) * f1 * at1);
    pout[idx] = f2b(v0) | ((unsigned)f2b(v1) << 16);
  }
}

// Wb in MFMA B-fragment order, bf16: Wb[((kt*2+nt)*64+lane)*8+j] = W1[o][korig]
__global__ __launch_bounds__(256) void k_prepw(const float* __restrict__ W,
                                               unsigned short* __restrict__ Wb) {
  int idx = blockIdx.x * 256 + threadIdx.x;  // 0 .. 393215
  int j = idx & 7;
  int lane = (idx >> 3) & 63;
  int nt = (idx >> 9) & 1;
  int kt = idx >> 10;
  int o = nt * 16 + (lane & 15);
  int k = kt * 32 + (lane >> 4) * 8 + j;
  int korig = (k & 31) * 384 + (k >> 5);
  Wb[idx] = f2b(W[(size_t)o * 12288 + korig]);
}

// MFMA MLP head: block = 16 graphs, 8 waves; wave = K-chunk of 1536 (48 tiles).
__global__ __launch_bounds__(512) void k_mlp(
    const unsigned short* __restrict__ pvec, const unsigned short* __restrict__ Wb,
    const float* __restrict__ lb1, const float* __restrict__ W2,
    const float* __restrict__ lb2, const float* __restrict__ W3,
    const float* __restrict__ lb3, float* __restrict__ out) {
  __shared__ float part[8][16][32];
  __shared__ float s1[16][32];
  __shared__ float s2[16][32];
  const int t = threadIdx.x;
  const int lane = t & 63, wv = t >> 6, lx = lane & 15, quad = lane >> 4;
  const int g0 = blockIdx.x * 16;
  const unsigned short* arow = pvec + (size_t)(g0 + lx) * 12288 + quad * 8;

  f32x4 acc0 = {0.f, 0.f, 0.f, 0.f}, acc1 = {0.f, 0.f, 0.f, 0.f};
  const int kt0 = wv * 48;
#pragma unroll 4
  for (int i = 0; i < 48; i++) {
    const int kt = kt0 + i;
    bf16x8 A = *(const bf16x8*)&arow[kt * 32];
    bf16x8 B0 = *(const bf16x8*)&Wb[((kt * 2 + 0) * 64 + lane) * 8];
    bf16x8 B1 = *(const bf16x8*)&Wb[((kt * 2 + 1) * 64 + lane) * 8];
    acc0 = __builtin_amdgcn_mfma_f32_16x16x32_bf16(A, B0, acc0, 0, 0, 0);
    acc1 = __builtin_amdgcn_mfma_f32_16x16x32_bf16(A, B1, acc1, 0, 0, 0);
  }
#pragma unroll
  for (int r = 0; r < 4; r++) {
    part[wv][quad * 4 + r][lx] = acc0[r];
    part[wv][quad * 4 + r][16 + lx] = acc1[r];
  }
  __syncthreads();
  {
    int g = t >> 5, o = t & 31;
    float s = 0.f;
#pragma unroll
    for (int w = 0; w < 8; w++) s += part[w][g][o];
    s1[g][o] = softplus_(s + lb1[o]);
  }
  __syncthreads();
  {
    int g = t >> 5, o = t & 31;
    float s = lb2[o];
    for (int kk = 0; kk < 32; kk++) s += s1[g][kk] * W2[o * 32 + kk];
    s2[g][o] = softplus_(s);
  }
  __syncthreads();
  if (t < 16) {
    float s = lb3[0];
    for (int kk = 0; kk < 32; kk++) s += s2[t][kk] * W3[kk];
    out[g0 + t] = softplus_(s);
  }
}

extern "C" void kernel_launch(void* const* d_in, const int* in_sizes, int n_in,
                              void* d_out, int out_size, void* d_ws, size_t ws_size,
                              hipStream_t stream) {
  const float* drug    = (const float*)d_in[0];
  const int*   ei      = (const int*)d_in[1];
  const float* protein = (const float*)d_in[3];
  const float* g1W = (const float*)d_in[4];
  const float* g1b = (const float*)d_in[5];
  const float* g2W = (const float*)d_in[6];
  const float* g2b = (const float*)d_in[7];
  const float* oW  = (const float*)d_in[8];
  const float* ob  = (const float*)d_in[9];
  const float* c1W = (const float*)d_in[10];
  const float* c1b = (const float*)d_in[11];
  const float* c2W = (const float*)d_in[12];
  const float* c2b = (const float*)d_in[13];
  const float* c3W = (const float*)d_in[14];
  const float* c3b = (const float*)d_in[15];
  const float* caW1 = (const float*)d_in[16];
  const float* caW2 = (const float*)d_in[17];
  const float* samW = (const float*)d_in[18];
  const float* samb = (const float*)d_in[19];
  const float* l1W = (const float*)d_in[20];
  const float* l1b = (const float*)d_in[21];
  const float* l2W = (const float*)d_in[22];
  const float* l2b = (const float*)d_in[23];
  const float* l3W = (const float*)d_in[24];
  const float* l3b = (const float*)d_in[25];

  // ---- workspace map: peak ~110 MiB (< 112 MiB known-safe) ----
  char* ws = (char*)d_ws;
  float* dinv  = (float*)(ws);                        // [0, 0.5M)
  int*   degi  = (int*)(ws + (size_t)524288);         // [0.5M, 1M)
  int*   cur   = (int*)(ws + (size_t)1048576);        // [1M, 1.5M) contiguous w/ degi
  int*   offs  = (int*)(ws + (size_t)1572864);        // [1.5M, 2M+4)
  int*   bsum  = (int*)(ws + (size_t)2621440);        // 2KB
  int*   bexcl = (int*)(ws + (size_t)2625536);        // 2KB
  int*   csr   = (int*)(ws + (size_t)3145728);        // [3M, 5M)
  unsigned short* gA = (unsigned short*)(ws + (size_t)5242880);   // [5M, 21M) bf16
  unsigned short* gB = (unsigned short*)(ws + (size_t)22020096);  // [21M, 37M) bf16
  float* x3    = (float*)(ws + (size_t)38797312);     // [37M, 69M) fp32
  // pvec (96 MiB) overlays gA/gB/x3 — all dead once k_cnn runs
  unsigned short* pvec = (unsigned short*)(ws + (size_t)5242880);     // [5M, 101M)
  float* pooled = (float*)(ws + (size_t)105906176);   // [101M, 103M)
  unsigned short* gout = (unsigned short*)(ws + (size_t)108003328);  // [103M, 109M) bf16
  unsigned short* Wb   = (unsigned short*)(ws + (size_t)114294784); // [109M, 109.75M)
  float* outp = (float*)d_out;

  // ---- CSR build + dinv ----
  k_zeroi<<<2 * NN / 256, 256, 0, stream>>>(degi);  // zeroes degi AND cur (contiguous)
  k_hist<<<EE / 256, 256, 0, stream>>>(ei, degi);
  k_dinv<<<NN / 256, 256, 0, stream>>>(degi, dinv);
  k_scan1<<<NN / 256, 256, 0, stream>>>(degi, offs /*incl temp*/, bsum);
  k_scan2<<<1, 512, 0, stream>>>(bsum, bexcl);
  k_scan3<<<NN / 256, 256, 0, stream>>>(offs, degi, bexcl, offs);
  k_scatter<<<EE / 256, 256, 0, stream>>>(ei, offs, cur, csr);
  k_prepw<<<(12288 * 32) / 256, 256, 0, stream>>>(l1W, Wb);

  // ---- GCN: g1 = dinv*(drug@W1) bf16; fused aggregate+mm layers ----
  k_mm1<<<NN / 4, 256, 0, stream>>>(drug, g1W, dinv, gA);
  k_layer<true, true><<<NN / 4, 256, 0, stream>>>(gA, offs, csr, dinv, g1b, g2W, gB, nullptr);
  k_layer<true, true><<<NN / 4, 256, 0, stream>>>(gB, offs, csr, dinv, g2b, g2W, gA, nullptr);
  k_layer<false, false><<<NN / 4, 256, 0, stream>>>(gA, offs, csr, dinv, g2b, g2W, nullptr, x3);

  // ---- pool + output linear ----
  k_pool<<<BB / 4, 256, 0, stream>>>(x3, pooled);
  k_outmm<<<BB / 16, 256, 0, stream>>>(pooled, oW, ob, gout);

  // ---- fused CNN chain + CBAM + maxpool ----
  k_cnn<<<BB, 1024, 0, stream>>>(gout, protein, c1W, c1b, c2W, c2b, c3W, c3b,
                                 caW1, caW2, samW, samb, pvec);

  // ---- MLP head (MFMA) ----
  k_mlp<<<BB / 16, 512, 0, stream>>>(pvec, Wb, l1b, l2W, l2b, l3W, l3b, outp);
}

// Round 7
// 708.144 us; speedup vs baseline: 3.6662x; 1.0762x over previous
//
#include <hip/hip_runtime.h>
#include <cstdint>
#include <cstddef>

#define NN 131072
#define EE 524288
#define BB 4096
#define LL 768
#define RS2 40  // LDS row stride in shorts (80 B): bank period 8 -> 2-way (free) vs 64 B's 8-way

typedef __attribute__((ext_vector_type(8))) short bf16x8;
typedef __attribute__((ext_vector_type(4))) float f32x4;
typedef __attribute__((ext_vector_type(2))) unsigned int uint2v;
typedef __attribute__((ext_vector_type(4))) unsigned int uint4v;

// ---------- helpers ----------
__device__ __forceinline__ float b2f(unsigned short u) {
  return __uint_as_float(((unsigned int)u) << 16);
}
__device__ __forceinline__ unsigned short f2b(float f) {
  unsigned int x = __float_as_uint(f);
  x += 0x7fff + ((x >> 16) & 1);  // RNE
  return (unsigned short)(x >> 16);
}
__device__ __forceinline__ float sigm(float x) { return 1.f / (1.f + expf(-x)); }
__device__ __forceinline__ float softplus_(float x) {
  return fmaxf(x, 0.f) + log1pf(expf(-fabsf(x)));
}

// ---------- CSR build ----------
__global__ __launch_bounds__(256) void k_zeroi(int* __restrict__ p) {
  p[blockIdx.x * 256 + threadIdx.x] = 0;
}
__global__ __launch_bounds__(256) void k_hist(const int* __restrict__ ei,
                                              int* __restrict__ degi) {
  int e = blockIdx.x * 256 + threadIdx.x;
  atomicAdd(&degi[ei[EE + e]], 1);
}
__global__ __launch_bounds__(256) void k_dinv(const int* __restrict__ degi,
                                              float* __restrict__ d) {
  int i = blockIdx.x * 256 + threadIdx.x;
  d[i] = rsqrtf((float)degi[i] + 1.0f);
}
__global__ __launch_bounds__(256) void k_scan1(const int* __restrict__ degi,
                                               int* __restrict__ incl,
                                               int* __restrict__ bsum) {
  __shared__ int s[256];
  int t = threadIdx.x;
  int i = blockIdx.x * 256 + t;
  s[t] = degi[i];
  __syncthreads();
  for (int off = 1; off < 256; off <<= 1) {
    int u = (t >= off) ? s[t - off] : 0;
    __syncthreads();
    s[t] += u;
    __syncthreads();
  }
  incl[i] = s[t];
  if (t == 255) bsum[blockIdx.x] = s[t];
}
__global__ __launch_bounds__(512) void k_scan2(const int* __restrict__ bsum,
                                               int* __restrict__ bexcl) {
  __shared__ int s[512];
  int t = threadIdx.x;
  s[t] = bsum[t];
  __syncthreads();
  int orig = s[t];
  for (int off = 1; off < 512; off <<= 1) {
    int u = (t >= off) ? s[t - off] : 0;
    __syncthreads();
    s[t] += u;
    __syncthreads();
  }
  bexcl[t] = s[t] - orig;
}
__global__ __launch_bounds__(256) void k_scan3(const int* __restrict__ incl,
                                               const int* __restrict__ degi,
                                               const int* __restrict__ bexcl,
                                               int* __restrict__ offs) {
  int t = threadIdx.x;
  int i = blockIdx.x * 256 + t;
  offs[i] = incl[i] - degi[i] + bexcl[blockIdx.x];
  if (i == 0) offs[NN] = EE;
}
__global__ __launch_bounds__(256) void k_scatter(const int* __restrict__ ei,
                                                 const int* __restrict__ offs,
                                                 int* __restrict__ cur,
                                                 int* __restrict__ csr) {
  int e = blockIdx.x * 256 + threadIdx.x;
  int dst = ei[EE + e];
  int pos = atomicAdd(&cur[dst], 1);
  csr[offs[dst] + pos] = ei[e];
}

// ---------- GCN dense parts (g buffers in bf16) ----------
__global__ __launch_bounds__(256) void k_mm1(const float* __restrict__ drug,
                                             const float* __restrict__ W,
                                             const float* __restrict__ dinv,
                                             unsigned short* __restrict__ g) {
  __shared__ float Ws[9 * 64];
  int t = threadIdx.x;
  for (int i = t; i < 576; i += 256) Ws[i] = W[i];
  __syncthreads();
  int node = blockIdx.x * 4 + (t >> 6);
  int f = t & 63;
  const float* dr = drug + (size_t)node * 9;
  float s = 0.f;
#pragma unroll
  for (int k = 0; k < 9; k++) s += dr[k] * Ws[k * 64 + f];
  g[(size_t)node * 64 + f] = f2b(dinv[node] * s);
}

// CSR pull + fused next-layer mm -> bf16 out. One wave per node, lane=feature.
template <bool TANH>
__global__ __launch_bounds__(256) void k_layer(const unsigned short* __restrict__ gin,
                                               const int* __restrict__ offs,
                                               const int* __restrict__ csr,
                                               const float* __restrict__ dinv,
                                               const float* __restrict__ bias,
                                               const float* __restrict__ W,
                                               unsigned short* __restrict__ outb) {
  __shared__ float Ws[64 * 64];
  __shared__ float xs[4][64];
  const int t = threadIdx.x;
  for (int i = t; i < 4096; i += 256) Ws[i] = W[i];
  const int d = blockIdx.x * 4 + (t >> 6);
  const int f = t & 63;
  const float di = dinv[d];
  const int j0 = offs[d], j1 = offs[d + 1];
  float acc = b2f(gin[(size_t)d * 64 + f]);
  int j = j0;
  for (; j + 4 <= j1; j += 4) {
    int s0 = csr[j], s1 = csr[j + 1], s2 = csr[j + 2], s3 = csr[j + 3];
    float v0 = b2f(gin[(size_t)s0 * 64 + f]);
    float v1 = b2f(gin[(size_t)s1 * 64 + f]);
    float v2 = b2f(gin[(size_t)s2 * 64 + f]);
    float v3 = b2f(gin[(size_t)s3 * 64 + f]);
    acc += (v0 + v1) + (v2 + v3);
  }
  for (; j < j1; j++) acc += b2f(gin[(size_t)csr[j] * 64 + f]);
  float v = di * acc + bias[f];
  if (TANH) v = tanhf(v);
  xs[t >> 6][f] = v;
  __syncthreads();
  const float* xr = xs[t >> 6];
  float s = 0.f;
#pragma unroll
  for (int k = 0; k < 64; k++) s += xr[k] * Ws[k * 64 + f];
  outb[(size_t)d * 64 + f] = f2b(di * s);
}

// Final GCN layer (no tanh, no mm) fused with per-graph max/mean pool.
// block = 1 graph (32 consecutive nodes), 512 thr: grp=t>>6 handles 4 nodes.
__global__ __launch_bounds__(512) void k_lastpool(const unsigned short* __restrict__ gin,
                                                  const int* __restrict__ offs,
                                                  const int* __restrict__ csr,
                                                  const float* __restrict__ dinv,
                                                  const float* __restrict__ bias,
                                                  float* __restrict__ pooled) {
  __shared__ float smax[8][64], ssum[8][64];
  const int t = threadIdx.x;
  const int f = t & 63, grp = t >> 6;
  const int g = blockIdx.x;
  const float bf = bias[f];
  float mx = -1e30f, sm = 0.f;
#pragma unroll
  for (int i = 0; i < 4; i++) {
    int d = g * 32 + grp * 4 + i;
    const float di = dinv[d];
    const int j0 = offs[d], j1 = offs[d + 1];
    float acc = b2f(gin[(size_t)d * 64 + f]);
    int j = j0;
    for (; j + 4 <= j1; j += 4) {
      int s0 = csr[j], s1 = csr[j + 1], s2 = csr[j + 2], s3 = csr[j + 3];
      acc += (b2f(gin[(size_t)s0 * 64 + f]) + b2f(gin[(size_t)s1 * 64 + f]))
           + (b2f(gin[(size_t)s2 * 64 + f]) + b2f(gin[(size_t)s3 * 64 + f]));
    }
    for (; j < j1; j++) acc += b2f(gin[(size_t)csr[j] * 64 + f]);
    float v = di * acc + bf;
    mx = fmaxf(mx, v);
    sm += v;
  }
  smax[grp][f] = mx;
  ssum[grp][f] = sm;
  __syncthreads();
  if (t < 64) {
    float m = smax[0][t], s = ssum[0][t];
#pragma unroll
    for (int w = 1; w < 8; w++) { m = fmaxf(m, smax[w][t]); s += ssum[w][t]; }
    pooled[(size_t)g * 128 + t] = m;
    pooled[(size_t)g * 128 + 64 + t] = s * (1.f / 32.f);
  }
}

// gout(bf16): 16 graphs/block
__global__ __launch_bounds__(256) void k_outmm(const float* __restrict__ pooled,
                                               const float* __restrict__ W,
                                               const float* __restrict__ bias,
                                               unsigned short* __restrict__ gout) {
  __shared__ float ps[16][128];
  int t = threadIdx.x;
  int g0 = blockIdx.x * 16;
  for (int i = t; i < 16 * 128; i += 256) ps[i >> 7][i & 127] = pooled[(size_t)g0 * 128 + i];
  __syncthreads();
  float a0[16], a1[16], a2[16];
#pragma unroll
  for (int j = 0; j < 16; j++) { a0[j] = 0.f; a1[j] = 0.f; a2[j] = 0.f; }
  for (int k = 0; k < 128; k++) {
    float w0 = W[k * 768 + t];
    float w1 = W[k * 768 + t + 256];
    float w2 = W[k * 768 + t + 512];
#pragma unroll
    for (int j = 0; j < 16; j++) {
      float p = ps[j][k];
      a0[j] += p * w0; a1[j] += p * w1; a2[j] += p * w2;
    }
  }
  float b0 = bias[t], b1 = bias[t + 256], b2 = bias[t + 512];
  for (int j = 0; j < 16; j++) {
    gout[(size_t)(g0 + j) * 768 + t]       = f2b(a0[j] + b0);
    gout[(size_t)(g0 + j) * 768 + t + 256] = f2b(a1[j] + b1);
    gout[(size_t)(g0 + j) * 768 + t + 512] = f2b(a2[j] + b2);
  }
}

// MFMA conv 32ch->32ch k=3 over position-major bf16 LDS (rows l+1, stride RS2).
// 8 waves x 6 position-tiles of 16. K tau-major: k = tau*32 + i.
template <bool STATS>
__device__ __forceinline__ void conv_mfma(const unsigned short* in, unsigned short* out,
                                          const unsigned short* Wt, const float* bias,
                                          int t, float tmax[2][4], float tsum[2][4]) {
  const int lane = t & 63, wv = t >> 6;
  const int lx = lane & 15, quad = lane >> 4;
  bf16x8 A[2][3];
  f32x4 cinit[2];
#pragma unroll
  for (int mt = 0; mt < 2; mt++) {
#pragma unroll
    for (int tau = 0; tau < 3; tau++)
      A[mt][tau] = *(const bf16x8*)&Wt[tau * 1024 + (mt * 16 + lx) * 32 + quad * 8];
#pragma unroll
    for (int r = 0; r < 4; r++) cinit[mt][r] = bias[mt * 16 + quad * 4 + r];
  }
  for (int n = 0; n < 6; n++) {
    const int l0 = (wv * 6 + n) * 16;
    bf16x8 Bf[3];
#pragma unroll
    for (int tau = 0; tau < 3; tau++)
      Bf[tau] = *(const bf16x8*)&in[(l0 + lx + tau) * RS2 + quad * 8];
#pragma unroll
    for (int mt = 0; mt < 2; mt++) {
      f32x4 acc = cinit[mt];
#pragma unroll
      for (int tau = 0; tau < 3; tau++)
        acc = __builtin_amdgcn_mfma_f32_16x16x32_bf16(A[mt][tau], Bf[tau], acc, 0, 0, 0);
      uint2v pk;
      pk.x = f2b(acc[0]) | ((unsigned)f2b(acc[1]) << 16);
      pk.y = f2b(acc[2]) | ((unsigned)f2b(acc[3]) << 16);
      *(uint2v*)&out[(l0 + lx + 1) * RS2 + mt * 16 + quad * 4] = pk;
      if (STATS) {
#pragma unroll
        for (int r = 0; r < 4; r++) {
          tmax[mt][r] = fmaxf(tmax[mt][r], acc[r]);
          tsum[mt][r] += acc[r];
        }
      }
    }
  }
}

// ---------- fully fused CNN chain (512 threads, padded-stride LDS) ----------
__global__ __launch_bounds__(512) void k_cnn(
    const unsigned short* __restrict__ gout, const float* __restrict__ protein,
    const float* __restrict__ W1, const float* __restrict__ b1,
    const float* __restrict__ W2, const float* __restrict__ b2,
    const float* __restrict__ W3, const float* __restrict__ b3,
    const float* __restrict__ caW1, const float* __restrict__ caW2,
    const float* __restrict__ samW, const float* __restrict__ samb,
    unsigned short* __restrict__ pvec) {
  __shared__ alignas(16) unsigned short h1t[770 * RS2];  // h1, then h3 (rows l+1)
  __shared__ alignas(16) unsigned short h2t[770 * RS2];  // comb(f32) -> h2 -> xm/xM/att(f32)
  __shared__ unsigned short W2t[3072], W3t[3072];        // [tau][o][i] bf16
  __shared__ float W1s[192];
  __shared__ float caW1s[512], caW2s[512];
  __shared__ float b1s[32], b2s[32], b3s[32], samWs[8];
  __shared__ float wmaxs[8][32], wsums[8][32];
  __shared__ float cmaxs[32], csums[32], t1buf[2][16], feats[32];
  float* h2f = (float*)h2t;
  const int t = threadIdx.x;
  const int b = blockIdx.x;
  const int lane = t & 63, wv = t >> 6, lx = lane & 15, quad = lane >> 4;

  // ---- S0: stage weights + comb; zero h1t halo rows ----
  for (int i = t; i < 192; i += 512) W1s[i] = W1[i];
  for (int i = t; i < 3072; i += 512) {
    int tau = i >> 10, rem = i & 1023, o = rem >> 5, ic = rem & 31;
    W2t[i] = f2b(W2[o * 96 + ic * 3 + tau]);
    W3t[i] = f2b(W3[o * 96 + ic * 3 + tau]);
  }
  if (t < 512) { caW1s[t] = caW1[t]; caW2s[t] = caW2[t]; }
  if (t < 32) { b1s[t] = b1[t]; b2s[t] = b2[t]; b3s[t] = b3[t]; }
  if (t >= 64 && t < 70) samWs[t - 64] = samW[t - 64];
  if (t == 70) samWs[6] = samb[0];
  if (t >= 128 && t < 192) {
    int z = t - 128;
    h1t[(z >= 32 ? 769 * RS2 : 0) + (z & 31)] = 0;
  }
  for (int i = t; i < 1544; i += 512) {
    int ch = (i >= 772) ? 1 : 0;
    int li = i - ch * 772;
    int l = li - 1;
    float v = 0.f;
    if (l >= 0 && l < LL)
      v = ch ? protein[(size_t)b * LL + l] : b2f(gout[(size_t)b * LL + l]);
    h2f[ch * 772 + li] = v;
  }
  __syncthreads();

  // ---- S1: conv1 (VALU), write position-major h1t ----
  {
    const int oct = t & 3;
    float wr[48], br[8];
#pragma unroll
    for (int a = 0; a < 8; a++) {
      int o = oct * 8 + a;
      br[a] = b1s[o];
#pragma unroll
      for (int q = 0; q < 6; q++) wr[a * 6 + q] = W1s[o * 6 + q];
    }
    const int lbase = t >> 2;  // 0..127
    for (int p = 0; p < 6; p++) {
      int l = lbase + p * 128;
      float c0 = h2f[l], c1 = h2f[l + 1], c2 = h2f[l + 2];
      float d0 = h2f[772 + l], d1 = h2f[772 + l + 1], d2 = h2f[772 + l + 2];
      uint4v pk;
#pragma unroll
      for (int a = 0; a < 4; a++) {
        const float* w0 = &wr[(2 * a) * 6];
        const float* w1 = &wr[(2 * a + 1) * 6];
        float s0 = br[2 * a]     + w0[0] * c0 + w0[1] * c1 + w0[2] * c2
                                 + w0[3] * d0 + w0[4] * d1 + w0[5] * d2;
        float s1 = br[2 * a + 1] + w1[0] * c0 + w1[1] * c1 + w1[2] * c2
                                 + w1[3] * d0 + w1[4] * d1 + w1[5] * d2;
        pk[a] = f2b(s0) | ((unsigned)f2b(s1) << 16);
      }
      *(uint4v*)&h1t[(l + 1) * RS2 + oct * 8] = pk;
    }
  }
  __syncthreads();

  // ---- S2: zero h2t halo rows (comb dead) + MFMA conv2: h1t -> h2t ----
  if (t < 64) h2t[(t >= 32 ? 769 * RS2 : 0) + (t & 31)] = 0;
  {
    float dm[2][4], ds[2][4];
    conv_mfma<false>(h1t, h2t, W2t, b2s, t, dm, ds);
  }
  __syncthreads();

  // ---- S3: MFMA conv3: h2t -> h1t (=h3), stats in registers ----
  float tmax[2][4], tsum[2][4];
#pragma unroll
  for (int mt = 0; mt < 2; mt++)
#pragma unroll
    for (int r = 0; r < 4; r++) { tmax[mt][r] = -1e30f; tsum[mt][r] = 0.f; }
  conv_mfma<true>(h2t, h1t, W3t, b3s, t, tmax, tsum);
#pragma unroll
  for (int mt = 0; mt < 2; mt++)
#pragma unroll
    for (int r = 0; r < 4; r++) {
      float m = tmax[mt][r], s = tsum[mt][r];
      for (int d = 1; d < 16; d <<= 1) {
        m = fmaxf(m, __shfl_xor(m, d));
        s += __shfl_xor(s, d);
      }
      if (lx == 0) {
        wmaxs[wv][mt * 16 + quad * 4 + r] = m;
        wsums[wv][mt * 16 + quad * 4 + r] = s;
      }
    }
  __syncthreads();

  // ---- S4: cross-wave stats + channel-attention MLP ----
  if (t < 32) {
    float m = wmaxs[0][t], s = wsums[0][t];
#pragma unroll
    for (int w = 1; w < 8; w++) { m = fmaxf(m, wmaxs[w][t]); s += wsums[w][t]; }
    cmaxs[t] = m;
    csums[t] = s;
  }
  __syncthreads();
  if (t < 32) {
    int j = t & 15;
    int mean = t >> 4;
    float s = 0.f;
    for (int o = 0; o < 32; o++) {
      float v = mean ? csums[o] * (1.f / 768.f) : cmaxs[o];
      s += v * caW1s[j * 32 + o];
    }
    t1buf[mean][j] = s;
  }
  __syncthreads();
  if (t < 32) {
    float m1 = 0.f, m2 = 0.f;
    for (int j = 0; j < 16; j++) {
      m1 += t1buf[0][j] * caW2s[t * 16 + j];
      m2 += t1buf[1][j] * caW2s[t * 16 + j];
    }
    feats[t] = sigm(fmaxf(m1, 0.f) + fmaxf(m2, 0.f));
  }
  __syncthreads();

  // ---- S5: spatial stats xm/xM per position (h2t dead -> f32 scratch) ----
  {
    const int oct = t & 3;
    float fr[8];
#pragma unroll
    for (int j = 0; j < 8; j++) fr[j] = feats[oct * 8 + j];
    for (int p = 0; p < 6; p++) {
      int idx = t + p * 512;
      int l = idx >> 2;
      bf16x8 rv = *(const bf16x8*)&h1t[(l + 1) * RS2 + oct * 8];
      float sm = 0.f, mx = -1e30f;
#pragma unroll
      for (int j = 0; j < 8; j++) {
        float v = b2f((unsigned short)rv[j]) * fr[j];
        sm += v;
        mx = fmaxf(mx, v);
      }
      sm += __shfl_xor(sm, 1);
      mx = fmaxf(mx, __shfl_xor(mx, 1));
      sm += __shfl_xor(sm, 2);
      mx = fmaxf(mx, __shfl_xor(mx, 2));
      if (oct == 0) {
        h2f[l] = sm * (1.f / 32.f);
        h2f[772 + l] = mx;
      }
    }
  }
  __syncthreads();

  // ---- S6: spatial attention conv + sigmoid ----
  for (int l = t; l < LL; l += 512) {
    float a = samWs[6];
#pragma unroll
    for (int k = 0; k < 3; k++) {
      int ll = l + k - 1;
      float vm = (ll >= 0 && ll < LL) ? h2f[ll] : 0.f;
      float vM = (ll >= 0 && ll < LL) ? h2f[772 + ll] : 0.f;
      a += samWs[k] * vm + samWs[3 + k] * vM;
    }
    h2f[1544 + l] = sigm(a);
  }
  __syncthreads();

  // ---- S7: scale + maxpool2, position-major pvec (coalesced u32 stores) ----
  unsigned* pout = (unsigned*)(pvec + (size_t)b * 12288);
  for (int p = 0; p < 12; p++) {
    int idx = t + p * 512;  // 0..6143
    int ch = (idx & 15) * 2;
    int lp = idx >> 4;
    unsigned a1 = *(const unsigned*)&h1t[(2 * lp + 1) * RS2 + ch];
    unsigned a2 = *(const unsigned*)&h1t[(2 * lp + 2) * RS2 + ch];
    float f0 = feats[ch], f1 = feats[ch + 1];
    float at0 = h2f[1544 + 2 * lp], at1 = h2f[1544 + 2 * lp + 1];
    float v0 = fmaxf(b2f((unsigned short)(a1 & 0xffff)) * f0 * at0,
                     b2f((unsigned short)(a2 & 0xffff)) * f0 * at1);
    float v1 = fmaxf(b2f((unsigned short)(a1 >> 16)) * f1 * at0,
                     b2f((unsigned short)(a2 >> 16)) * f1 * at1);
    pout[idx] = f2b(v0) | ((unsigned)f2b(v1) << 16);
  }
}

// Wb in MFMA B-fragment order, bf16: Wb[((kt*2+nt)*64+lane)*8+j] = W1[o][korig]
__global__ __launch_bounds__(256) void k_prepw(const float* __restrict__ W,
                                               unsigned short* __restrict__ Wb) {
  int idx = blockIdx.x * 256 + threadIdx.x;  // 0 .. 393215
  int j = idx & 7;
  int lane = (idx >> 3) & 63;
  int nt = (idx >> 9) & 1;
  int kt = idx >> 10;
  int o = nt * 16 + (lane & 15);
  int k = kt * 32 + (lane >> 4) * 8 + j;
  int korig = (k & 31) * 384 + (k >> 5);
  Wb[idx] = f2b(W[(size_t)o * 12288 + korig]);
}

// MFMA MLP head: block = 16 graphs, 8 waves; wave = K-chunk of 1536 (48 tiles).
__global__ __launch_bounds__(512) void k_mlp(
    const unsigned short* __restrict__ pvec, const unsigned short* __restrict__ Wb,
    const float* __restrict__ lb1, const float* __restrict__ W2,
    const float* __restrict__ lb2, const float* __restrict__ W3,
    const float* __restrict__ lb3, float* __restrict__ out) {
  __shared__ float part[8][16][32];
  __shared__ float s1[16][32];
  __shared__ float s2[16][32];
  const int t = threadIdx.x;
  const int lane = t & 63, wv = t >> 6, lx = lane & 15, quad = lane >> 4;
  const int g0 = blockIdx.x * 16;
  const unsigned short* arow = pvec + (size_t)(g0 + lx) * 12288 + quad * 8;

  f32x4 acc0 = {0.f, 0.f, 0.f, 0.f}, acc1 = {0.f, 0.f, 0.f, 0.f};
  const int kt0 = wv * 48;
#pragma unroll 4
  for (int i = 0; i < 48; i++) {
    const int kt = kt0 + i;
    bf16x8 A = *(const bf16x8*)&arow[kt * 32];
    bf16x8 B0 = *(const bf16x8*)&Wb[((kt * 2 + 0) * 64 + lane) * 8];
    bf16x8 B1 = *(const bf16x8*)&Wb[((kt * 2 + 1) * 64 + lane) * 8];
    acc0 = __builtin_amdgcn_mfma_f32_16x16x32_bf16(A, B0, acc0, 0, 0, 0);
    acc1 = __builtin_amdgcn_mfma_f32_16x16x32_bf16(A, B1, acc1, 0, 0, 0);
  }
#pragma unroll
  for (int r = 0; r < 4; r++) {
    part[wv][quad * 4 + r][lx] = acc0[r];
    part[wv][quad * 4 + r][16 + lx] = acc1[r];
  }
  __syncthreads();
  {
    int g = t >> 5, o = t & 31;
    float s = 0.f;
#pragma unroll
    for (int w = 0; w < 8; w++) s += part[w][g][o];
    s1[g][o] = softplus_(s + lb1[o]);
  }
  __syncthreads();
  {
    int g = t >> 5, o = t & 31;
    float s = lb2[o];
    for (int kk = 0; kk < 32; kk++) s += s1[g][kk] * W2[o * 32 + kk];
    s2[g][o] = softplus_(s);
  }
  __syncthreads();
  if (t < 16) {
    float s = lb3[0];
    for (int kk = 0; kk < 32; kk++) s += s2[t][kk] * W3[kk];
    out[g0 + t] = softplus_(s);
  }
}

extern "C" void kernel_launch(void* const* d_in, const int* in_sizes, int n_in,
                              void* d_out, int out_size, void* d_ws, size_t ws_size,
                              hipStream_t stream) {
  const float* drug    = (const float*)d_in[0];
  const int*   ei      = (const int*)d_in[1];
  const float* protein = (const float*)d_in[3];
  const float* g1W = (const float*)d_in[4];
  const float* g1b = (const float*)d_in[5];
  const float* g2W = (const float*)d_in[6];
  const float* g2b = (const float*)d_in[7];
  const float* oW  = (const float*)d_in[8];
  const float* ob  = (const float*)d_in[9];
  const float* c1W = (const float*)d_in[10];
  const float* c1b = (const float*)d_in[11];
  const float* c2W = (const float*)d_in[12];
  const float* c2b = (const float*)d_in[13];
  const float* c3W = (const float*)d_in[14];
  const float* c3b = (const float*)d_in[15];
  const float* caW1 = (const float*)d_in[16];
  const float* caW2 = (const float*)d_in[17];
  const float* samW = (const float*)d_in[18];
  const float* samb = (const float*)d_in[19];
  const float* l1W = (const float*)d_in[20];
  const float* l1b = (const float*)d_in[21];
  const float* l2W = (const float*)d_in[22];
  const float* l2b = (const float*)d_in[23];
  const float* l3W = (const float*)d_in[24];
  const float* l3b = (const float*)d_in[25];

  // ---- workspace map: peak ~110 MiB (< 112 MiB known-safe) ----
  char* ws = (char*)d_ws;
  float* dinv  = (float*)(ws);                        // [0, 0.5M)
  int*   degi  = (int*)(ws + (size_t)524288);         // [0.5M, 1M)
  int*   cur   = (int*)(ws + (size_t)1048576);        // [1M, 1.5M) contiguous w/ degi
  int*   offs  = (int*)(ws + (size_t)1572864);        // [1.5M, 2M+4)
  int*   bsum  = (int*)(ws + (size_t)2621440);        // 2KB
  int*   bexcl = (int*)(ws + (size_t)2625536);        // 2KB
  int*   csr   = (int*)(ws + (size_t)3145728);        // [3M, 5M)
  unsigned short* gA = (unsigned short*)(ws + (size_t)5242880);   // [5M, 21M) bf16
  unsigned short* gB = (unsigned short*)(ws + (size_t)22020096);  // [21M, 37M) bf16
  // pvec (96 MiB) overlays gA/gB — dead once k_cnn runs
  unsigned short* pvec = (unsigned short*)(ws + (size_t)5242880);     // [5M, 101M)
  float* pooled = (float*)(ws + (size_t)105906176);   // [101M, 103M)
  unsigned short* gout = (unsigned short*)(ws + (size_t)108003328);  // [103M, 109M) bf16
  unsigned short* Wb   = (unsigned short*)(ws + (size_t)114294784); // [109M, 109.75M)
  float* outp = (float*)d_out;

  // ---- CSR build + dinv ----
  k_zeroi<<<2 * NN / 256, 256, 0, stream>>>(degi);  // zeroes degi AND cur (contiguous)
  k_hist<<<EE / 256, 256, 0, stream>>>(ei, degi);
  k_dinv<<<NN / 256, 256, 0, stream>>>(degi, dinv);
  k_scan1<<<NN / 256, 256, 0, stream>>>(degi, offs /*incl temp*/, bsum);
  k_scan2<<<1, 512, 0, stream>>>(bsum, bexcl);
  k_scan3<<<NN / 256, 256, 0, stream>>>(offs, degi, bexcl, offs);
  k_scatter<<<EE / 256, 256, 0, stream>>>(ei, offs, cur, csr);
  k_prepw<<<(12288 * 32) / 256, 256, 0, stream>>>(l1W, Wb);

  // ---- GCN: g1 = dinv*(drug@W1) bf16; fused aggregate+mm layers; last layer + pool ----
  k_mm1<<<NN / 4, 256, 0, stream>>>(drug, g1W, dinv, gA);
  k_layer<true><<<NN / 4, 256, 0, stream>>>(gA, offs, csr, dinv, g1b, g2W, gB);
  k_layer<true><<<NN / 4, 256, 0, stream>>>(gB, offs, csr, dinv, g2b, g2W, gA);
  k_lastpool<<<BB, 512, 0, stream>>>(gA, offs, csr, dinv, g2b, pooled);

  // ---- output linear ----
  k_outmm<<<BB / 16, 256, 0, stream>>>(pooled, oW, ob, gout);

  // ---- fused CNN chain + CBAM + maxpool ----
  k_cnn<<<BB, 512, 0, stream>>>(gout, protein, c1W, c1b, c2W, c2b, c3W, c3b,
                                caW1, caW2, samW, samb, pvec);

  // ---- MLP head (MFMA) ----
  k_mlp<<<BB / 16, 512, 0, stream>>>(pvec, Wb, l1b, l2W, l2b, l3W, l3b, outp);
}

// Round 8
// 699.404 us; speedup vs baseline: 3.7120x; 1.0125x over previous
//
#include <hip/hip_runtime.h>
#include <cstdint>
#include <cstddef>

#define NN 131072
#define EE 524288
#define BB 4096
#define LL 768
#define RS2 40  // LDS row stride in shorts (80 B)

typedef __attribute__((ext_vector_type(8))) short bf16x8;
typedef __attribute__((ext_vector_type(4))) float f32x4;
typedef __attribute__((ext_vector_type(2))) unsigned int uint2v;
typedef __attribute__((ext_vector_type(4))) unsigned int uint4v;

// ---------- helpers ----------
__device__ __forceinline__ float b2f(unsigned short u) {
  return __uint_as_float(((unsigned int)u) << 16);
}
__device__ __forceinline__ unsigned short f2b(float f) {
  unsigned int x = __float_as_uint(f);
  x += 0x7fff + ((x >> 16) & 1);  // RNE
  return (unsigned short)(x >> 16);
}
// packed 2x f32 -> bf16x2 in one v_cvt_pk_bf16_f32 when available
__device__ __forceinline__ unsigned f2b2(float lo, float hi) {
#if __has_builtin(__builtin_amdgcn_cvt_pk_bf16_f32)
  typedef __attribute__((ext_vector_type(2))) __bf16 bf16v2;
  bf16v2 r = __builtin_amdgcn_cvt_pk_bf16_f32(lo, hi);
  return __builtin_bit_cast(unsigned, r);
#else
  return (unsigned)f2b(lo) | ((unsigned)f2b(hi) << 16);
#endif
}
__device__ __forceinline__ float sigm(float x) { return 1.f / (1.f + expf(-x)); }
__device__ __forceinline__ float softplus_(float x) {
  return fmaxf(x, 0.f) + log1pf(expf(-fabsf(x)));
}

// ---------- CSR build ----------
__global__ __launch_bounds__(256) void k_zeroi(int* __restrict__ p) {
  p[blockIdx.x * 256 + threadIdx.x] = 0;
}
__global__ __launch_bounds__(256) void k_hist(const int* __restrict__ ei,
                                              int* __restrict__ degi) {
  int e = blockIdx.x * 256 + threadIdx.x;
  atomicAdd(&degi[ei[EE + e]], 1);
}
__global__ __launch_bounds__(256) void k_dinv(const int* __restrict__ degi,
                                              float* __restrict__ d) {
  int i = blockIdx.x * 256 + threadIdx.x;
  d[i] = rsqrtf((float)degi[i] + 1.0f);
}
__global__ __launch_bounds__(256) void k_scan1(const int* __restrict__ degi,
                                               int* __restrict__ incl,
                                               int* __restrict__ bsum) {
  __shared__ int s[256];
  int t = threadIdx.x;
  int i = blockIdx.x * 256 + t;
  s[t] = degi[i];
  __syncthreads();
  for (int off = 1; off < 256; off <<= 1) {
    int u = (t >= off) ? s[t - off] : 0;
    __syncthreads();
    s[t] += u;
    __syncthreads();
  }
  incl[i] = s[t];
  if (t == 255) bsum[blockIdx.x] = s[t];
}
__global__ __launch_bounds__(512) void k_scan2(const int* __restrict__ bsum,
                                               int* __restrict__ bexcl) {
  __shared__ int s[512];
  int t = threadIdx.x;
  s[t] = bsum[t];
  __syncthreads();
  int orig = s[t];
  for (int off = 1; off < 512; off <<= 1) {
    int u = (t >= off) ? s[t - off] : 0;
    __syncthreads();
    s[t] += u;
    __syncthreads();
  }
  bexcl[t] = s[t] - orig;
}
__global__ __launch_bounds__(256) void k_scan3(const int* __restrict__ incl,
                                               const int* __restrict__ degi,
                                               const int* __restrict__ bexcl,
                                               int* __restrict__ offs) {
  int t = threadIdx.x;
  int i = blockIdx.x * 256 + t;
  offs[i] = incl[i] - degi[i] + bexcl[blockIdx.x];
  if (i == 0) offs[NN] = EE;
}
__global__ __launch_bounds__(256) void k_scatter(const int* __restrict__ ei,
                                                 const int* __restrict__ offs,
                                                 int* __restrict__ cur,
                                                 int* __restrict__ csr) {
  int e = blockIdx.x * 256 + threadIdx.x;
  int dst = ei[EE + e];
  int pos = atomicAdd(&cur[dst], 1);
  csr[offs[dst] + pos] = ei[e];
}

// ---------- GCN dense parts (g buffers in bf16) ----------
__global__ __launch_bounds__(256) void k_mm1(const float* __restrict__ drug,
                                             const float* __restrict__ W,
                                             const float* __restrict__ dinv,
                                             unsigned short* __restrict__ g) {
  __shared__ float Ws[9 * 64];
  int t = threadIdx.x;
  for (int i = t; i < 576; i += 256) Ws[i] = W[i];
  __syncthreads();
  int node = blockIdx.x * 4 + (t >> 6);
  int f = t & 63;
  const float* dr = drug + (size_t)node * 9;
  float s = 0.f;
#pragma unroll
  for (int k = 0; k < 9; k++) s += dr[k] * Ws[k * 64 + f];
  g[(size_t)node * 64 + f] = f2b(dinv[node] * s);
}

// CSR pull + fused next-layer mm -> bf16 out. One wave per node, lane=feature.
template <bool TANH>
__global__ __launch_bounds__(256) void k_layer(const unsigned short* __restrict__ gin,
                                               const int* __restrict__ offs,
                                               const int* __restrict__ csr,
                                               const float* __restrict__ dinv,
                                               const float* __restrict__ bias,
                                               const float* __restrict__ W,
                                               unsigned short* __restrict__ outb) {
  __shared__ float Ws[64 * 64];
  __shared__ float xs[4][64];
  const int t = threadIdx.x;
  for (int i = t; i < 4096; i += 256) Ws[i] = W[i];
  const int d = blockIdx.x * 4 + (t >> 6);
  const int f = t & 63;
  const float di = dinv[d];
  const int j0 = offs[d], j1 = offs[d + 1];
  float acc = b2f(gin[(size_t)d * 64 + f]);
  int j = j0;
  for (; j + 4 <= j1; j += 4) {
    int s0 = csr[j], s1 = csr[j + 1], s2 = csr[j + 2], s3 = csr[j + 3];
    float v0 = b2f(gin[(size_t)s0 * 64 + f]);
    float v1 = b2f(gin[(size_t)s1 * 64 + f]);
    float v2 = b2f(gin[(size_t)s2 * 64 + f]);
    float v3 = b2f(gin[(size_t)s3 * 64 + f]);
    acc += (v0 + v1) + (v2 + v3);
  }
  for (; j < j1; j++) acc += b2f(gin[(size_t)csr[j] * 64 + f]);
  float v = di * acc + bias[f];
  if (TANH) v = tanhf(v);
  xs[t >> 6][f] = v;
  __syncthreads();
  const float* xr = xs[t >> 6];
  float s = 0.f;
#pragma unroll
  for (int k = 0; k < 64; k++) s += xr[k] * Ws[k * 64 + f];
  outb[(size_t)d * 64 + f] = f2b(di * s);
}

// Final GCN layer fused with per-graph max/mean pool. block = 1 graph, 512 thr.
__global__ __launch_bounds__(512) void k_lastpool(const unsigned short* __restrict__ gin,
                                                  const int* __restrict__ offs,
                                                  const int* __restrict__ csr,
                                                  const float* __restrict__ dinv,
                                                  const float* __restrict__ bias,
                                                  float* __restrict__ pooled) {
  __shared__ float smax[8][64], ssum[8][64];
  const int t = threadIdx.x;
  const int f = t & 63, grp = t >> 6;
  const int g = blockIdx.x;
  const float bf = bias[f];
  float mx = -1e30f, sm = 0.f;
#pragma unroll
  for (int i = 0; i < 4; i++) {
    int d = g * 32 + grp * 4 + i;
    const float di = dinv[d];
    const int j0 = offs[d], j1 = offs[d + 1];
    float acc = b2f(gin[(size_t)d * 64 + f]);
    int j = j0;
    for (; j + 4 <= j1; j += 4) {
      int s0 = csr[j], s1 = csr[j + 1], s2 = csr[j + 2], s3 = csr[j + 3];
      acc += (b2f(gin[(size_t)s0 * 64 + f]) + b2f(gin[(size_t)s1 * 64 + f]))
           + (b2f(gin[(size_t)s2 * 64 + f]) + b2f(gin[(size_t)s3 * 64 + f]));
    }
    for (; j < j1; j++) acc += b2f(gin[(size_t)csr[j] * 64 + f]);
    float v = di * acc + bf;
    mx = fmaxf(mx, v);
    sm += v;
  }
  smax[grp][f] = mx;
  ssum[grp][f] = sm;
  __syncthreads();
  if (t < 64) {
    float m = smax[0][t], s = ssum[0][t];
#pragma unroll
    for (int w = 1; w < 8; w++) { m = fmaxf(m, smax[w][t]); s += ssum[w][t]; }
    pooled[(size_t)g * 128 + t] = m;
    pooled[(size_t)g * 128 + 64 + t] = s * (1.f / 32.f);
  }
}

// gout(bf16): 16 graphs/block
__global__ __launch_bounds__(256) void k_outmm(const float* __restrict__ pooled,
                                               const float* __restrict__ W,
                                               const float* __restrict__ bias,
                                               unsigned short* __restrict__ gout) {
  __shared__ float ps[16][128];
  int t = threadIdx.x;
  int g0 = blockIdx.x * 16;
  for (int i = t; i < 16 * 128; i += 256) ps[i >> 7][i & 127] = pooled[(size_t)g0 * 128 + i];
  __syncthreads();
  float a0[16], a1[16], a2[16];
#pragma unroll
  for (int j = 0; j < 16; j++) { a0[j] = 0.f; a1[j] = 0.f; a2[j] = 0.f; }
  for (int k = 0; k < 128; k++) {
    float w0 = W[k * 768 + t];
    float w1 = W[k * 768 + t + 256];
    float w2 = W[k * 768 + t + 512];
#pragma unroll
    for (int j = 0; j < 16; j++) {
      float p = ps[j][k];
      a0[j] += p * w0; a1[j] += p * w1; a2[j] += p * w2;
    }
  }
  float b0 = bias[t], b1 = bias[t + 256], b2 = bias[t + 512];
  for (int j = 0; j < 16; j++) {
    gout[(size_t)(g0 + j) * 768 + t]       = f2b(a0[j] + b0);
    gout[(size_t)(g0 + j) * 768 + t + 256] = f2b(a1[j] + b1);
    gout[(size_t)(g0 + j) * 768 + t + 512] = f2b(a2[j] + b2);
  }
}

// MFMA conv2 32ch->32ch k=3 over position-major bf16 LDS (rows l+1, stride RS2).
__device__ __forceinline__ void conv_mfma2(const unsigned short* in, unsigned short* out,
                                           const unsigned short* Wt, const float* bias,
                                           int t) {
  const int lane = t & 63, wv = t >> 6;
  const int lx = lane & 15, quad = lane >> 4;
  bf16x8 A[2][3];
  f32x4 cinit[2];
#pragma unroll
  for (int mt = 0; mt < 2; mt++) {
#pragma unroll
    for (int tau = 0; tau < 3; tau++)
      A[mt][tau] = *(const bf16x8*)&Wt[tau * 1024 + (mt * 16 + lx) * 32 + quad * 8];
#pragma unroll
    for (int r = 0; r < 4; r++) cinit[mt][r] = bias[mt * 16 + quad * 4 + r];
  }
#pragma unroll
  for (int n = 0; n < 6; n++) {
    const int l0 = (wv * 6 + n) * 16;
    bf16x8 Bf[3];
#pragma unroll
    for (int tau = 0; tau < 3; tau++)
      Bf[tau] = *(const bf16x8*)&in[(l0 + lx + tau) * RS2 + quad * 8];
#pragma unroll
    for (int mt = 0; mt < 2; mt++) {
      f32x4 acc = cinit[mt];
#pragma unroll
      for (int tau = 0; tau < 3; tau++)
        acc = __builtin_amdgcn_mfma_f32_16x16x32_bf16(A[mt][tau], Bf[tau], acc, 0, 0, 0);
      uint2v pk;
      pk.x = f2b2(acc[0], acc[1]);
      pk.y = f2b2(acc[2], acc[3]);
      *(uint2v*)&out[(l0 + lx + 1) * RS2 + mt * 16 + quad * 4] = pk;
    }
  }
}

// ---------- fully fused CNN chain (512 thr); conv3 output lives in registers ----------
__global__ __launch_bounds__(512) void k_cnn(
    const unsigned short* __restrict__ gout, const float* __restrict__ protein,
    const float* __restrict__ W1, const float* __restrict__ b1,
    const float* __restrict__ W2, const float* __restrict__ b2,
    const float* __restrict__ W3, const float* __restrict__ b3,
    const float* __restrict__ caW1, const float* __restrict__ caW2,
    const float* __restrict__ samW, const float* __restrict__ samb,
    unsigned short* __restrict__ pvec) {
  __shared__ alignas(16) unsigned short h1t[770 * RS2];  // h1
  __shared__ alignas(16) unsigned short h2t[770 * RS2];  // comb(f32) -> h2 -> xm/xM/att(f32)
  __shared__ unsigned short W2t[3072], W3t[3072];        // [tau][o][i] bf16
  __shared__ float W1s[192];
  __shared__ float caW1s[512], caW2s[512];
  __shared__ float b1s[32], b2s[32], b3s[32], samWs[8];
  __shared__ float wmaxs[8][32], wsums[8][32];
  __shared__ float cmaxs[32], csums[32], t1buf[2][16], feats[32];
  float* h2f = (float*)h2t;
  const int t = threadIdx.x;
  const int b = blockIdx.x;
  const int lane = t & 63, wv = t >> 6, lx = lane & 15, quad = lane >> 4;

  // ---- S0: stage weights + comb; zero h1t halo rows ----
  for (int i = t; i < 192; i += 512) W1s[i] = W1[i];
  for (int i = t; i < 3072; i += 512) {
    int tau = i >> 10, rem = i & 1023, o = rem >> 5, ic = rem & 31;
    W2t[i] = f2b(W2[o * 96 + ic * 3 + tau]);
    W3t[i] = f2b(W3[o * 96 + ic * 3 + tau]);
  }
  if (t < 512) { caW1s[t] = caW1[t]; caW2s[t] = caW2[t]; }
  if (t < 32) { b1s[t] = b1[t]; b2s[t] = b2[t]; b3s[t] = b3[t]; }
  if (t >= 64 && t < 70) samWs[t - 64] = samW[t - 64];
  if (t == 70) samWs[6] = samb[0];
  if (t >= 128 && t < 192) {
    int z = t - 128;
    h1t[(z >= 32 ? 769 * RS2 : 0) + (z & 31)] = 0;
  }
  for (int i = t; i < 1544; i += 512) {
    int ch = (i >= 772) ? 1 : 0;
    int li = i - ch * 772;
    int l = li - 1;
    float v = 0.f;
    if (l >= 0 && l < LL)
      v = ch ? protein[(size_t)b * LL + l] : b2f(gout[(size_t)b * LL + l]);
    h2f[ch * 772 + li] = v;
  }
  __syncthreads();

  // ---- S1: conv1 (VALU), write position-major h1t ----
  {
    const int oct = t & 3;
    float wr[48], br[8];
#pragma unroll
    for (int a = 0; a < 8; a++) {
      int o = oct * 8 + a;
      br[a] = b1s[o];
#pragma unroll
      for (int q = 0; q < 6; q++) wr[a * 6 + q] = W1s[o * 6 + q];
    }
    const int lbase = t >> 2;  // 0..127
    for (int p = 0; p < 6; p++) {
      int l = lbase + p * 128;
      float c0 = h2f[l], c1 = h2f[l + 1], c2 = h2f[l + 2];
      float d0 = h2f[772 + l], d1 = h2f[772 + l + 1], d2 = h2f[772 + l + 2];
      uint4v pk;
#pragma unroll
      for (int a = 0; a < 4; a++) {
        const float* w0 = &wr[(2 * a) * 6];
        const float* w1 = &wr[(2 * a + 1) * 6];
        float s0 = br[2 * a]     + w0[0] * c0 + w0[1] * c1 + w0[2] * c2
                                 + w0[3] * d0 + w0[4] * d1 + w0[5] * d2;
        float s1 = br[2 * a + 1] + w1[0] * c0 + w1[1] * c1 + w1[2] * c2
                                 + w1[3] * d0 + w1[4] * d1 + w1[5] * d2;
        pk[a] = f2b2(s0, s1);
      }
      *(uint4v*)&h1t[(l + 1) * RS2 + oct * 8] = pk;
    }
  }
  __syncthreads();

  // ---- S2: zero h2t halo rows (comb dead) + MFMA conv2: h1t -> h2t ----
  if (t < 64) h2t[(t >= 32 ? 769 * RS2 : 0) + (t & 31)] = 0;
  conv_mfma2(h1t, h2t, W2t, b2s, t);
  __syncthreads();

  // ---- S3: MFMA conv3: h2t -> registers a3[n][mt], stats in registers ----
  f32x4 a3[6][2];
  float tmax[2][4], tsum[2][4];
#pragma unroll
  for (int mt = 0; mt < 2; mt++)
#pragma unroll
    for (int r = 0; r < 4; r++) { tmax[mt][r] = -1e30f; tsum[mt][r] = 0.f; }
  {
    bf16x8 A[2][3];
    f32x4 cinit[2];
#pragma unroll
    for (int mt = 0; mt < 2; mt++) {
#pragma unroll
      for (int tau = 0; tau < 3; tau++)
        A[mt][tau] = *(const bf16x8*)&W3t[tau * 1024 + (mt * 16 + lx) * 32 + quad * 8];
#pragma unroll
      for (int r = 0; r < 4; r++) cinit[mt][r] = b3s[mt * 16 + quad * 4 + r];
    }
#pragma unroll
    for (int n = 0; n < 6; n++) {
      const int l0 = (wv * 6 + n) * 16;
      bf16x8 Bf[3];
#pragma unroll
      for (int tau = 0; tau < 3; tau++)
        Bf[tau] = *(const bf16x8*)&h2t[(l0 + lx + tau) * RS2 + quad * 8];
#pragma unroll
      for (int mt = 0; mt < 2; mt++) {
        f32x4 acc = cinit[mt];
#pragma unroll
        for (int tau = 0; tau < 3; tau++)
          acc = __builtin_amdgcn_mfma_f32_16x16x32_bf16(A[mt][tau], Bf[tau], acc, 0, 0, 0);
        a3[n][mt] = acc;
#pragma unroll
        for (int r = 0; r < 4; r++) {
          tmax[mt][r] = fmaxf(tmax[mt][r], acc[r]);
          tsum[mt][r] += acc[r];
        }
      }
    }
  }
  // per-channel stats: reduce over the 16 lx lanes
#pragma unroll
  for (int mt = 0; mt < 2; mt++)
#pragma unroll
    for (int r = 0; r < 4; r++) {
      float m = tmax[mt][r], s = tsum[mt][r];
      for (int d = 1; d < 16; d <<= 1) {
        m = fmaxf(m, __shfl_xor(m, d));
        s += __shfl_xor(s, d);
      }
      if (lx == 0) {
        wmaxs[wv][mt * 16 + quad * 4 + r] = m;
        wsums[wv][mt * 16 + quad * 4 + r] = s;
      }
    }
  __syncthreads();

  // ---- S4: cross-wave stats + channel-attention MLP ----
  if (t < 32) {
    float m = wmaxs[0][t], s = wsums[0][t];
#pragma unroll
    for (int w = 1; w < 8; w++) { m = fmaxf(m, wmaxs[w][t]); s += wsums[w][t]; }
    cmaxs[t] = m;
    csums[t] = s;
  }
  __syncthreads();
  if (t < 32) {
    int j = t & 15;
    int mean = t >> 4;
    float s = 0.f;
    for (int o = 0; o < 32; o++) {
      float v = mean ? csums[o] * (1.f / 768.f) : cmaxs[o];
      s += v * caW1s[j * 32 + o];
    }
    t1buf[mean][j] = s;
  }
  __syncthreads();
  if (t < 32) {
    float m1 = 0.f, m2 = 0.f;
    for (int j = 0; j < 16; j++) {
      m1 += t1buf[0][j] * caW2s[t * 16 + j];
      m2 += t1buf[1][j] * caW2s[t * 16 + j];
    }
    feats[t] = sigm(fmaxf(m1, 0.f) + fmaxf(m2, 0.f));
  }
  __syncthreads();

  // ---- S5': spatial stats from registers; quad-shuffle gives all 32 ch per l ----
  float frq[2][4];
#pragma unroll
  for (int mt = 0; mt < 2; mt++)
#pragma unroll
    for (int r = 0; r < 4; r++) frq[mt][r] = feats[mt * 16 + quad * 4 + r];
#pragma unroll
  for (int n = 0; n < 6; n++) {
    int l = (wv * 6 + n) * 16 + lx;
    float sm = 0.f, mx = -1e30f;
#pragma unroll
    for (int mt = 0; mt < 2; mt++)
#pragma unroll
      for (int r = 0; r < 4; r++) {
        float v = a3[n][mt][r] * frq[mt][r];
        sm += v;
        mx = fmaxf(mx, v);
      }
    sm += __shfl_xor(sm, 16); mx = fmaxf(mx, __shfl_xor(mx, 16));
    sm += __shfl_xor(sm, 32); mx = fmaxf(mx, __shfl_xor(mx, 32));
    if (quad == 0) {
      h2f[l] = sm * (1.f / 32.f);
      h2f[772 + l] = mx;
    }
  }
  __syncthreads();

  // ---- S6: spatial attention conv + sigmoid ----
  for (int l = t; l < LL; l += 512) {
    float a = samWs[6];
#pragma unroll
    for (int k = 0; k < 3; k++) {
      int ll = l + k - 1;
      float vm = (ll >= 0 && ll < LL) ? h2f[ll] : 0.f;
      float vM = (ll >= 0 && ll < LL) ? h2f[772 + ll] : 0.f;
      a += samWs[k] * vm + samWs[3 + k] * vM;
    }
    h2f[1544 + l] = sigm(a);
  }
  __syncthreads();

  // ---- S7': scale + maxpool2 via lane-pair shuffle, store pvec from registers ----
#pragma unroll
  for (int n = 0; n < 6; n++) {
    int l = (wv * 6 + n) * 16 + lx;
    float at = h2f[1544 + l];
    float m[2][4];
#pragma unroll
    for (int mt = 0; mt < 2; mt++)
#pragma unroll
      for (int r = 0; r < 4; r++) {
        float v = a3[n][mt][r] * frq[mt][r] * at;
        m[mt][r] = fmaxf(v, __shfl_xor(v, 1));
      }
    if (!(lx & 1)) {
      int lp = l >> 1;
#pragma unroll
      for (int mt = 0; mt < 2; mt++) {
        uint2v pk;
        pk.x = f2b2(m[mt][0], m[mt][1]);
        pk.y = f2b2(m[mt][2], m[mt][3]);
        *(uint2v*)&pvec[(size_t)b * 12288 + lp * 32 + mt * 16 + quad * 4] = pk;
      }
    }
  }
}

// Wb in MFMA B-fragment order, bf16: Wb[((kt*2+nt)*64+lane)*8+j] = W1[o][korig]
__global__ __launch_bounds__(256) void k_prepw(const float* __restrict__ W,
                                               unsigned short* __restrict__ Wb) {
  int idx = blockIdx.x * 256 + threadIdx.x;  // 0 .. 393215
  int j = idx & 7;
  int lane = (idx >> 3) & 63;
  int nt = (idx >> 9) & 1;
  int kt = idx >> 10;
  int o = nt * 16 + (lane & 15);
  int k = kt * 32 + (lane >> 4) * 8 + j;
  int korig = (k & 31) * 384 + (k >> 5);
  Wb[idx] = f2b(W[(size_t)o * 12288 + korig]);
}

// MLP layer-1 partials: block = (16 graphs, 1/4 of K); 1024 blocks total.
__global__ __launch_bounds__(512) void k_mlp1(
    const unsigned short* __restrict__ pvec, const unsigned short* __restrict__ Wb,
    float* __restrict__ partial) {
  __shared__ float part[8][16][32];
  const int t = threadIdx.x;
  const int lane = t & 63, wv = t >> 6, lx = lane & 15, quad = lane >> 4;
  const int g0 = (blockIdx.x >> 2) * 16;
  const int kc = blockIdx.x & 3;
  const unsigned short* arow = pvec + (size_t)(g0 + lx) * 12288 + quad * 8;

  f32x4 acc0 = {0.f, 0.f, 0.f, 0.f}, acc1 = {0.f, 0.f, 0.f, 0.f};
  const int kt0 = kc * 96 + wv * 12;
#pragma unroll 4
  for (int i = 0; i < 12; i++) {
    const int kt = kt0 + i;
    bf16x8 A = *(const bf16x8*)&arow[kt * 32];
    bf16x8 B0 = *(const bf16x8*)&Wb[((kt * 2 + 0) * 64 + lane) * 8];
    bf16x8 B1 = *(const bf16x8*)&Wb[((kt * 2 + 1) * 64 + lane) * 8];
    acc0 = __builtin_amdgcn_mfma_f32_16x16x32_bf16(A, B0, acc0, 0, 0, 0);
    acc1 = __builtin_amdgcn_mfma_f32_16x16x32_bf16(A, B1, acc1, 0, 0, 0);
  }
#pragma unroll
  for (int r = 0; r < 4; r++) {
    part[wv][quad * 4 + r][lx] = acc0[r];
    part[wv][quad * 4 + r][16 + lx] = acc1[r];
  }
  __syncthreads();
  {
    int g = t >> 5, o = t & 31;
    float s = 0.f;
#pragma unroll
    for (int w = 0; w < 8; w++) s += part[w][g][o];
    partial[((size_t)kc * BB + g0 + g) * 32 + o] = s;
  }
}

// MLP tail: reduce 4 K-chunk partials + softplus chain + layers 2,3.
__global__ __launch_bounds__(512) void k_mlp2(
    const float* __restrict__ partial,
    const float* __restrict__ lb1, const float* __restrict__ W2,
    const float* __restrict__ lb2, const float* __restrict__ W3,
    const float* __restrict__ lb3, float* __restrict__ out) {
  __shared__ float s1[16][32];
  __shared__ float s2[16][32];
  const int t = threadIdx.x;
  const int g0 = blockIdx.x * 16;
  {
    int g = t >> 5, o = t & 31;
    float s = lb1[o];
#pragma unroll
    for (int kc = 0; kc < 4; kc++) s += partial[((size_t)kc * BB + g0 + g) * 32 + o];
    s1[g][o] = softplus_(s);
  }
  __syncthreads();
  {
    int g = t >> 5, o = t & 31;
    float s = lb2[o];
    for (int kk = 0; kk < 32; kk++) s += s1[g][kk] * W2[o * 32 + kk];
    s2[g][o] = softplus_(s);
  }
  __syncthreads();
  if (t < 16) {
    float s = lb3[0];
    for (int kk = 0; kk < 32; kk++) s += s2[t][kk] * W3[kk];
    out[g0 + t] = softplus_(s);
  }
}

extern "C" void kernel_launch(void* const* d_in, const int* in_sizes, int n_in,
                              void* d_out, int out_size, void* d_ws, size_t ws_size,
                              hipStream_t stream) {
  const float* drug    = (const float*)d_in[0];
  const int*   ei      = (const int*)d_in[1];
  const float* protein = (const float*)d_in[3];
  const float* g1W = (const float*)d_in[4];
  const float* g1b = (const float*)d_in[5];
  const float* g2W = (const float*)d_in[6];
  const float* g2b = (const float*)d_in[7];
  const float* oW  = (const float*)d_in[8];
  const float* ob  = (const float*)d_in[9];
  const float* c1W = (const float*)d_in[10];
  const float* c1b = (const float*)d_in[11];
  const float* c2W = (const float*)d_in[12];
  const float* c2b = (const float*)d_in[13];
  const float* c3W = (const float*)d_in[14];
  const float* c3b = (const float*)d_in[15];
  const float* caW1 = (const float*)d_in[16];
  const float* caW2 = (const float*)d_in[17];
  const float* samW = (const float*)d_in[18];
  const float* samb = (const float*)d_in[19];
  const float* l1W = (const float*)d_in[20];
  const float* l1b = (const float*)d_in[21];
  const float* l2W = (const float*)d_in[22];
  const float* l2b = (const float*)d_in[23];
  const float* l3W = (const float*)d_in[24];
  const float* l3b = (const float*)d_in[25];

  // ---- workspace map: peak exactly 112 MiB (known-safe) ----
  char* ws = (char*)d_ws;
  float* dinv  = (float*)(ws);                        // [0, 0.5M)
  int*   degi  = (int*)(ws + (size_t)524288);         // [0.5M, 1M)
  int*   cur   = (int*)(ws + (size_t)1048576);        // [1M, 1.5M) contiguous w/ degi
  int*   offs  = (int*)(ws + (size_t)1572864);        // [1.5M, 2M+4)
  int*   bsum  = (int*)(ws + (size_t)2621440);        // 2KB
  int*   bexcl = (int*)(ws + (size_t)2625536);        // 2KB
  int*   csr   = (int*)(ws + (size_t)3145728);        // [3M, 5M)
  unsigned short* gA = (unsigned short*)(ws + (size_t)5242880);   // [5M, 21M) bf16
  unsigned short* gB = (unsigned short*)(ws + (size_t)22020096);  // [21M, 37M) bf16
  // pvec (96 MiB) overlays gA/gB — dead once k_cnn runs
  unsigned short* pvec = (unsigned short*)(ws + (size_t)5242880);     // [5M, 101M)
  float* pooled = (float*)(ws + (size_t)105906176);   // [101M, 103M)
  unsigned short* gout = (unsigned short*)(ws + (size_t)108003328);  // [103M, 109M) bf16
  unsigned short* Wb   = (unsigned short*)(ws + (size_t)114294784);  // [109M, +768K)
  float* partial = (float*)(ws + (size_t)115343360);  // [110M, 112M)
  float* outp = (float*)d_out;

  // ---- CSR build + dinv ----
  k_zeroi<<<2 * NN / 256, 256, 0, stream>>>(degi);  // zeroes degi AND cur (contiguous)
  k_hist<<<EE / 256, 256, 0, stream>>>(ei, degi);
  k_dinv<<<NN / 256, 256, 0, stream>>>(degi, dinv);
  k_scan1<<<NN / 256, 256, 0, stream>>>(degi, offs /*incl temp*/, bsum);
  k_scan2<<<1, 512, 0, stream>>>(bsum, bexcl);
  k_scan3<<<NN / 256, 256, 0, stream>>>(offs, degi, bexcl, offs);
  k_scatter<<<EE / 256, 256, 0, stream>>>(ei, offs, cur, csr);
  k_prepw<<<(12288 * 32) / 256, 256, 0, stream>>>(l1W, Wb);

  // ---- GCN ----
  k_mm1<<<NN / 4, 256, 0, stream>>>(drug, g1W, dinv, gA);
  k_layer<true><<<NN / 4, 256, 0, stream>>>(gA, offs, csr, dinv, g1b, g2W, gB);
  k_layer<true><<<NN / 4, 256, 0, stream>>>(gB, offs, csr, dinv, g2b, g2W, gA);
  k_lastpool<<<BB, 512, 0, stream>>>(gA, offs, csr, dinv, g2b, pooled);

  // ---- output linear ----
  k_outmm<<<BB / 16, 256, 0, stream>>>(pooled, oW, ob, gout);

  // ---- fused CNN chain + CBAM + maxpool ----
  k_cnn<<<BB, 512, 0, stream>>>(gout, protein, c1W, c1b, c2W, c2b, c3W, c3b,
                                caW1, caW2, samW, samb, pvec);

  // ---- MLP head (MFMA, K-split 4x) ----
  k_mlp1<<<(BB / 16) * 4, 512, 0, stream>>>(pvec, Wb, partial);
  k_mlp2<<<BB / 16, 512, 0, stream>>>(partial, l1b, l2W, l2b, l3W, l3b, outp);
}